// Round 3
// baseline (21459.013 us; speedup 1.0000x reference)
//
#include <hip/hip_runtime.h>
#include <hip/hip_bf16.h>
#include <cmath>

#define T_LEN 4096
#define BATCH 16
typedef __hip_bfloat16 bf16;

// dt codes: 0 = f32, 1 = bf16
__device__ __forceinline__ float ldx(const void* p, int dt, size_t i) {
    return dt ? __bfloat162float(((const bf16*)p)[i]) : ((const float*)p)[i];
}
__device__ __forceinline__ void stx(void* p, int dt, size_t i, float v) {
    if (dt) ((bf16*)p)[i] = __float2bfloat16(v);
    else ((float*)p)[i] = v;
}
__device__ __forceinline__ int rdt(const int* dflag, int code) {
    // code 0/1 fixed; code 2 = external tensor, resolve via flag
    return code == 2 ? *dflag : code;
}

// ---------------------------------------------------------------- dtype probe
// True f32 N(0,1) data never has |v| >= 1e30; a bf16 buffer misread as f32
// puts mantissa bits in the exponent -> ~20% NaN/huge. flag=1 => bf16 world.
__global__ void detect_kernel(const float* __restrict__ x, int* __restrict__ flag) {
    __shared__ int s[256];
    int tid = threadIdx.x;
    int bad = 0;
    for (int i = tid; i < 2048; i += 256) {
        float v = x[i];
        if (!(fabsf(v) < 1e30f)) bad = 1;
    }
    s[tid] = bad;
    __syncthreads();
    for (int off = 128; off > 0; off >>= 1) {
        if (tid < off) s[tid] |= s[tid + off];
        __syncthreads();
    }
    if (tid == 0) *flag = s[0];
}

// ---------------------------------------------------------------- spk norm
__global__ void spk_norm_kernel(const int* __restrict__ dflag,
                                const void* __restrict__ spk,
                                float* __restrict__ out) {
    const int f = *dflag;
    int s = blockIdx.x, d = threadIdx.x;
    float v = ldx(spk, f, (size_t)s * 128 + d);
    __shared__ float red[128];
    red[d] = v * v;
    __syncthreads();
    for (int off = 64; off > 0; off >>= 1) {
        if (d < off) red[d] += red[d + off];
        __syncthreads();
    }
    float rs = rsqrtf(red[0]);
    out[s * 128 + d] = v * rs;
}

// ---------------------------------------------------------------- ye gather
// ye is per-slice: [nb,128,T]; y is indexed with absolute batch b0+bz.
__global__ void ye_kernel(const int* __restrict__ y, int b0,
                          const float* __restrict__ spk_n,
                          float* __restrict__ ye) {
    int bz = blockIdx.y;
    int t = blockIdx.x * 256 + threadIdx.x;
    int idx = y[(size_t)(b0 + bz) * T_LEN + t];
    const float* src = spk_n + (size_t)idx * 128;
    float* dst = ye + (size_t)bz * 128 * T_LEN + t;
#pragma unroll 4
    for (int d = 0; d < 128; d++) dst[(size_t)d * T_LEN] = src[d];
}

// ---------------------------------------------------------------- conv
// out[b,oc,t] = bias[oc] + sum_{ic,k} W_eff[oc,ic,k] * in[b,ic,t+k-PAD]
// wmode 0: w [Cout,Cin,K].  wmode 1: w [Cin,wCout,K], W_eff[o,i,k]=w[i,o,K-1-k]
// in = concat(in1 [.,C1,.], in2 [.,C2,.]).  dt codes per rdt().
// b1off/boff: absolute-batch offsets for in1 and out (slicing support);
// in2 (ye) is always per-slice (offset 0).
// ilayout (in1): 0 = [b,C1,T], 1 = [b,T,C1].  olayout: 0=[b,Cout,T], 1=[b,T,Cout]
template <int KK>
__global__ __launch_bounds__(256) void conv_kernel(
    const int* __restrict__ dflag,
    const void* __restrict__ in1, int d1, int C1, int ilayout, int b1off,
    const void* __restrict__ in2, int d2, int C2,
    const void* __restrict__ w, int wmode, int wCout,
    const void* __restrict__ bias,
    void* __restrict__ out, int odt, int Cout, int olayout, int boff) {
    constexpr int PAD = (KK - 1) / 2;
    constexpr int TILE_T = 64;
    constexpr int SIN_W = TILE_T + KK - 1;
    const int F = *dflag;
    const int D1 = (d1 == 2) ? F : d1;
    const int D2 = (d2 == 2) ? F : d2;
    const int ODT = (odt == 2) ? F : odt;
    const int t0 = blockIdx.x * TILE_T;
    const int oc0 = blockIdx.y * 64;
    const int b = blockIdx.z;
    const int tid = threadIdx.x;
    const int tx = tid & 15;   // t group (4 t each)
    const int ty = tid >> 4;   // oc group (4 oc each)
    const int Cin = C1 + C2;

    __shared__ __align__(16) float sIn[16 * SIN_W];
    __shared__ __align__(16) float sW[16 * KK * 64];

    float acc[4][4] = {};

    for (int ic0 = 0; ic0 < Cin; ic0 += 16) {
        const void* in;
        int cbase, ilay, cstride, dt, bb;
        if (ic0 < C1) { in = in1; cbase = ic0; ilay = ilayout; cstride = C1; dt = D1; bb = b + b1off; }
        else          { in = in2; cbase = ic0 - C1; ilay = 0;  cstride = C2; dt = D2; bb = b; }
        for (int idx = tid; idx < 16 * SIN_W; idx += 256) {
            int icl = idx / SIN_W;
            int tl = idx % SIN_W;
            int gt = t0 + tl - PAD;
            float v = 0.f;
            if (gt >= 0 && gt < T_LEN) {
                int c = cbase + icl;
                size_t off = (ilay == 0)
                                 ? ((size_t)bb * cstride + c) * T_LEN + gt
                                 : ((size_t)bb * T_LEN + gt) * cstride + c;
                v = ldx(in, dt, off);
            }
            sIn[idx] = v;
        }
        for (int idx = tid; idx < 16 * KK * 64; idx += 256) {
            int ocl = idx & 63;
            int r = idx >> 6;
            int icl = r / KK, k = r % KK;
            int oc = oc0 + ocl, ic = ic0 + icl;
            float v = 0.f;
            if (oc < Cout) {
                size_t off = (wmode == 0)
                                 ? ((size_t)oc * Cin + ic) * KK + k
                                 : ((size_t)ic * wCout + oc) * KK + (KK - 1 - k);
                v = ldx(w, F, off);
            }
            sW[idx] = v;
        }
        __syncthreads();

#pragma unroll
        for (int icl = 0; icl < 16; icl++) {
            const float* si = &sIn[icl * SIN_W + tx * 4];
            float iv[4 + KK - 1];
            float4 va = *(const float4*)si;
            iv[0] = va.x; iv[1] = va.y; iv[2] = va.z; iv[3] = va.w;
            if constexpr (KK == 5) {
                float4 vb = *(const float4*)(si + 4);
                iv[4] = vb.x; iv[5] = vb.y; iv[6] = vb.z; iv[7] = vb.w;
            }
#pragma unroll
            for (int k = 0; k < KK; k++) {
                float4 wv = *(const float4*)&sW[(icl * KK + k) * 64 + ty * 4];
                float wa[4] = {wv.x, wv.y, wv.z, wv.w};
#pragma unroll
                for (int i = 0; i < 4; i++)
#pragma unroll
                    for (int j = 0; j < 4; j++)
                        acc[i][j] += wa[i] * iv[k + j];
            }
        }
        __syncthreads();
    }

    const int bo = b + boff;
#pragma unroll
    for (int i = 0; i < 4; i++) {
        int oc = oc0 + ty * 4 + i;
        if (oc >= Cout) continue;
        float bv = ldx(bias, F, oc);
#pragma unroll
        for (int j = 0; j < 4; j++) {
            float v = acc[i][j] + bv;
            size_t off = (olayout == 0)
                             ? ((size_t)bo * Cout + oc) * T_LEN + t0 + tx * 4 + j
                             : ((size_t)bo * T_LEN + t0 + tx * 4 + j) * Cout + oc;
            stx(out, ODT, off, v);
        }
    }
}

// ---------------------------------------------------------------- LN+LeakyReLU (f32, in-place)
__global__ __launch_bounds__(256) void ln_lrelu_kernel(
    const int* __restrict__ dflag, float* buf,
    const void* __restrict__ g, const void* __restrict__ bt, int C) {
    const int f = *dflag;
    int b = blockIdx.y;
    int t = blockIdx.x * 256 + threadIdx.x;
    float* base = buf + (size_t)b * C * T_LEN + t;
    float s = 0.f, s2 = 0.f;
    for (int c = 0; c < C; c++) {
        float v = base[(size_t)c * T_LEN];
        s += v;
        s2 += v * v;
    }
    float mean = s / C;
    float var = s2 / C - mean * mean;
    float rstd = rsqrtf(var + 1e-5f);
    for (int c = 0; c < C; c++) {
        float v = (base[(size_t)c * T_LEN] - mean) * rstd * ldx(g, f, c) +
                  ldx(bt, f, c);
        base[(size_t)c * T_LEN] = v >= 0.f ? v : 0.2f * v;
    }
}

// ---------------------------------------------------------------- LN+GLU
__global__ __launch_bounds__(256) void ln_glu_kernel(
    const int* __restrict__ dflag,
    const bf16* __restrict__ in, bf16* __restrict__ out,
    const void* __restrict__ g, const void* __restrict__ bt, int C) {
    const int f = *dflag;
    int b = blockIdx.y;
    int t = blockIdx.x * 256 + threadIdx.x;
    const bf16* base = in + (size_t)b * C * T_LEN + t;
    float s = 0.f, s2 = 0.f;
    for (int c = 0; c < C; c++) {
        float v = __bfloat162float(base[(size_t)c * T_LEN]);
        s += v;
        s2 += v * v;
    }
    float mean = s / C;
    float var = s2 / C - mean * mean;
    float rstd = rsqrtf(var + 1e-5f);
    int H = C >> 1;
    bf16* ob = out + (size_t)b * H * T_LEN + t;
    for (int c = 0; c < H; c++) {
        float a = (__bfloat162float(base[(size_t)c * T_LEN]) - mean) * rstd *
                      ldx(g, f, c) + ldx(bt, f, c);
        float gv = (__bfloat162float(base[(size_t)(c + H) * T_LEN]) - mean) * rstd *
                       ldx(g, f, c + H) + ldx(bt, f, c + H);
        ob[(size_t)c * T_LEN] = __float2bfloat16(a / (1.f + expf(-gv)));
    }
}

// ---------------------------------------------------------------- VQ
__global__ __launch_bounds__(256) void vq_kernel(
    const int* __restrict__ dflag,
    const float* __restrict__ z, const void* __restrict__ cb,
    bf16* __restrict__ zvq) {
    const int f = *dflag;
    int b = blockIdx.y;
    int t0 = blockIdx.x * 64;
    int tid = threadIdx.x;
    int tl = tid & 63;
    int sub = tid >> 6;

    __shared__ __align__(16) float sZ[64 * 64];    // [d][t]
    __shared__ __align__(16) float sCB[128 * 64];  // code chunk (f32)
    __shared__ float sDist[4 * 64];
    __shared__ int sIdx[4 * 64];

    for (int idx = tid; idx < 64 * 64; idx += 256) {
        int d = idx >> 6, t = idx & 63;
        sZ[idx] = z[((size_t)b * 64 + d) * T_LEN + t0 + t];
    }
    __syncthreads();
    float zz = 0.f;
#pragma unroll 8
    for (int d = 0; d < 64; d++) {
        float v = sZ[d * 64 + tl];
        zz += v * v;
    }

    float best = 3.4e38f;
    int bidx = 0;
    for (int chunk = 0; chunk < 4; chunk++) {
        for (int idx = tid; idx < 128 * 64; idx += 256)
            sCB[idx] = ldx(cb, f, (size_t)chunk * 128 * 64 + idx);
        __syncthreads();
        for (int cc = 0; cc < 32; cc++) {
            int c = sub * 32 + cc;
            const float* cp = &sCB[c * 64];
            float dot = 0.f, nn = 0.f;
#pragma unroll 8
            for (int d = 0; d < 64; d++) {
                float cv = cp[d];
                dot += sZ[d * 64 + tl] * cv;
                nn += cv * cv;
            }
            float dist = zz + nn - 2.f * dot;
            int gc = chunk * 128 + c;
            if (dist < best) { best = dist; bidx = gc; }
        }
        __syncthreads();
    }
    sDist[sub * 64 + tl] = best;
    sIdx[sub * 64 + tl] = bidx;
    __syncthreads();
    if (sub == 0) {
        for (int s = 1; s < 4; s++) {
            float d2 = sDist[s * 64 + tl];
            int i2 = sIdx[s * 64 + tl];
            if (d2 < best || (d2 == best && i2 < bidx)) { best = d2; bidx = i2; }
        }
        sIdx[tl] = bidx;
    }
    __syncthreads();
    int fidx = sIdx[tl];
    for (int d = sub * 16; d < sub * 16 + 16; d++)
        zvq[((size_t)b * 64 + d) * T_LEN + t0 + tl] =
            __float2bfloat16(ldx(cb, f, (size_t)fidx * 64 + d));
}

// ---------------------------------------------------------------- launch
extern "C" void kernel_launch(void* const* d_in, const int* in_sizes, int n_in,
                              void* d_out, int out_size, void* d_ws,
                              size_t ws_size, hipStream_t stream) {
    const void* x = d_in[0];
    const int* y = (const int*)d_in[1];
    const void* enc_w1 = d_in[2];
    const void* enc_b1 = d_in[3];
    const void* enc_g1 = d_in[4];
    const void* enc_bt1 = d_in[5];
    const void* enc_w2 = d_in[6];
    const void* enc_b2 = d_in[7];
    const void* enc_g2 = d_in[8];
    const void* enc_bt2 = d_in[9];
    const void* enc_w3 = d_in[10];
    const void* enc_b3 = d_in[11];
    const void* enc_g3 = d_in[12];
    const void* enc_bt3 = d_in[13];
    const void* mlp_w = d_in[14];
    const void* mlp_b = d_in[15];
    const void* codebook = d_in[16];
    const void* spk_emb = d_in[17];
    const void* dec_w1 = d_in[18];
    const void* dec_b1 = d_in[19];
    const void* dec_g1 = d_in[20];
    const void* dec_bt1 = d_in[21];
    const void* dec_w2 = d_in[22];
    const void* dec_b2 = d_in[23];
    const void* dec_g2 = d_in[24];
    const void* dec_bt2 = d_in[25];
    const void* dec_w3 = d_in[26];
    const void* dec_b3 = d_in[27];

    const size_t YE_B = (size_t)128 * T_LEN * 4;   // ye f32 per batch
    const size_t U_B = (size_t)512 * T_LEN * 4;    // enc ping f32 == dec P bf16 x1024
    const size_t V_B = (size_t)512 * T_LEN * 4;    // enc pong f32 ⊇ zb,zvq,Q
    const size_t PER_B = YE_B + U_B + V_B;         // 18.87 MB / batch
    const size_t HDR_B = 256 + 65536;

    int nb = BATCH;
    while (nb > 1 && HDR_B + (size_t)nb * PER_B > ws_size) nb >>= 1;

    char* p = (char*)d_ws;
    int* dflag = (int*)p;                   p += 256;
    float* spk_n = (float*)p;               p += 65536;
    float* ye = (float*)p;                  p += (size_t)nb * YE_B;
    char* Uc = p;                           p += (size_t)nb * U_B;
    char* Vc = p;
    float* U = (float*)Uc;                              // [nb,512,T] f32
    bf16* P = (bf16*)Uc;                                // [nb,1024,T] bf16
    float* V = (float*)Vc;                              // [nb,512,T] f32
    float* zb = (float*)Vc;                             // [nb,64,T] f32
    bf16* zvq = (bf16*)(Vc + (size_t)nb * 64 * T_LEN * 4);  // [nb,64,T] bf16
    bf16* Q = (bf16*)Vc;                                // [nb,512,T] bf16

    dim3 blk(256);

    detect_kernel<<<1, 256, 0, stream>>>((const float*)x, dflag);
    spk_norm_kernel<<<128, 128, 0, stream>>>(dflag, spk_emb, spk_n);

    for (int b0 = 0; b0 < BATCH; b0 += nb) {
        dim3 gLN(T_LEN / 256, nb);

        ye_kernel<<<dim3(T_LEN / 256, nb), blk, 0, stream>>>(y, b0, spk_n, ye);

        // encoder (f32 intermediates); x indexed with absolute batch (b1off)
        conv_kernel<5><<<dim3(64, 8, nb), blk, 0, stream>>>(
            dflag, x, 2, 80, 1, b0, nullptr, 0, 0, enc_w1, 0, 512, enc_b1,
            U, 0, 512, 0, 0);
        ln_lrelu_kernel<<<gLN, blk, 0, stream>>>(dflag, U, enc_g1, enc_bt1, 512);
        conv_kernel<5><<<dim3(64, 8, nb), blk, 0, stream>>>(
            dflag, U, 0, 512, 0, 0, nullptr, 0, 0, enc_w2, 0, 512, enc_b2,
            V, 0, 512, 0, 0);
        ln_lrelu_kernel<<<gLN, blk, 0, stream>>>(dflag, V, enc_g2, enc_bt2, 512);
        conv_kernel<5><<<dim3(64, 8, nb), blk, 0, stream>>>(
            dflag, V, 0, 512, 0, 0, nullptr, 0, 0, enc_w3, 0, 512, enc_b3,
            U, 0, 512, 0, 0);
        ln_lrelu_kernel<<<gLN, blk, 0, stream>>>(dflag, U, enc_g3, enc_bt3, 512);

        conv_kernel<1><<<dim3(64, 1, nb), blk, 0, stream>>>(
            dflag, U, 0, 512, 0, 0, nullptr, 0, 0, mlp_w, 0, 64, mlp_b,
            zb, 0, 64, 0, 0);

        vq_kernel<<<dim3(T_LEN / 64, nb), blk, 0, stream>>>(dflag, zb, codebook, zvq);

        // decoder (bf16 intermediates); out indexed with absolute batch (boff)
        conv_kernel<5><<<dim3(64, 16, nb), blk, 0, stream>>>(
            dflag, zvq, 1, 64, 0, 0, ye, 0, 128, dec_w1, 1, 1024, dec_b1,
            P, 1, 1024, 0, 0);
        ln_glu_kernel<<<gLN, blk, 0, stream>>>(dflag, P, Q, dec_g1, dec_bt1, 1024);
        conv_kernel<5><<<dim3(64, 16, nb), blk, 0, stream>>>(
            dflag, Q, 1, 512, 0, 0, ye, 0, 128, dec_w2, 1, 1024, dec_b2,
            P, 1, 1024, 0, 0);
        ln_glu_kernel<<<gLN, blk, 0, stream>>>(dflag, P, Q, dec_g2, dec_bt2, 1024);
        conv_kernel<5><<<dim3(64, 2, nb), blk, 0, stream>>>(
            dflag, Q, 1, 512, 0, 0, ye, 0, 128, dec_w3, 1, 80, dec_b3,
            d_out, 2, 80, 1, b0);
    }
}

// Round 4
// 5605.587 us; speedup vs baseline: 3.8281x; 3.8281x over previous
//
#include <hip/hip_runtime.h>
#include <hip/hip_bf16.h>
#include <cmath>

#define T_LEN 4096
#define BATCH 16
typedef __hip_bfloat16 bf16;
typedef unsigned short u16;
typedef float f32x4 __attribute__((ext_vector_type(4)));
typedef short s16x8 __attribute__((ext_vector_type(8)));

__device__ __forceinline__ float ldx(const void* p, int dt, size_t i) {
    return dt ? __bfloat162float(((const bf16*)p)[i]) : ((const float*)p)[i];
}
__device__ __forceinline__ void stx(void* p, int dt, size_t i, float v) {
    if (dt) ((bf16*)p)[i] = __float2bfloat16(v);
    else ((float*)p)[i] = v;
}
__device__ __forceinline__ u16 f2b(float v) {
    bf16 h = __float2bfloat16(v);
    return *(u16*)&h;
}
__device__ __forceinline__ float b2f(u16 u) {
    return __bfloat162float(*(const bf16*)&u);
}

// ---------------------------------------------------------------- dtype probe
__global__ void detect_kernel(const float* __restrict__ x, int* __restrict__ flag) {
    __shared__ int s[256];
    int tid = threadIdx.x;
    int bad = 0;
    for (int i = tid; i < 2048; i += 256) {
        float v = x[i];
        if (!(fabsf(v) < 1e30f)) bad = 1;
    }
    s[tid] = bad;
    __syncthreads();
    for (int off = 128; off > 0; off >>= 1) {
        if (tid < off) s[tid] |= s[tid + off];
        __syncthreads();
    }
    if (tid == 0) *flag = s[0];
}

// ---------------------------------------------------------------- spk norm
__global__ void spk_norm_kernel(const int* __restrict__ dflag,
                                const void* __restrict__ spk,
                                float* __restrict__ out) {
    const int f = *dflag;
    int s = blockIdx.x, d = threadIdx.x;
    float v = ldx(spk, f, (size_t)s * 128 + d);
    __shared__ float red[128];
    red[d] = v * v;
    __syncthreads();
    for (int off = 64; off > 0; off >>= 1) {
        if (d < off) red[d] += red[d + off];
        __syncthreads();
    }
    float rs = rsqrtf(red[0]);
    out[s * 128 + d] = v * rs;
}

// ---------------------------------------------------------------- weight repack
// dst layout: [K][ocp][Cinp] bf16 (zero-padded). wmode0: src [Cout,Cin,K];
// wmode1 (convT): src [Cin,Cout,K], W_eff[o][i][k] = src[i][o][K-1-k].
__global__ void repack_kernel(const int* __restrict__ dflag,
                              const void* __restrict__ src, int wmode,
                              int Cout, int Cin, int K, int ocp, int Cinp,
                              bf16* __restrict__ dsthi, bf16* __restrict__ dstlo) {
    const int F = *dflag;
    size_t total = (size_t)K * ocp * Cinp;
    size_t stride = (size_t)gridDim.x * 256;
    for (size_t i = (size_t)blockIdx.x * 256 + threadIdx.x; i < total; i += stride) {
        int k = (int)(i / ((size_t)ocp * Cinp));
        int r = (int)(i % ((size_t)ocp * Cinp));
        int oc = r / Cinp, ic = r % Cinp;
        float v = 0.f;
        if (oc < Cout && ic < Cin) {
            size_t off = wmode ? (((size_t)ic * Cout + oc) * K + (K - 1 - k))
                               : (((size_t)oc * Cin + ic) * K + k);
            v = ldx(src, F, off);
        }
        bf16 h = __float2bfloat16(v);
        dsthi[i] = h;
        if (dstlo) dstlo[i] = __float2bfloat16(v - __bfloat162float(h));
    }
}

// ---------------------------------------------------------------- x prep
// x external [b_abs][t][80] -> xp [b][t][192] bf16: hi cols [0,96) (pad 0),
// lo cols [96,192).
__global__ void xprep_kernel(const int* __restrict__ dflag,
                             const void* __restrict__ x, int b0,
                             bf16* __restrict__ xp) {
    const int F = *dflag;
    int b = blockIdx.y;
    int t = blockIdx.x * 256 + threadIdx.x;
    size_t src = ((size_t)(b0 + b) * T_LEN + t) * 80;
    u16* row = (u16*)xp + ((size_t)b * T_LEN + t) * 192;
    for (int c4 = 0; c4 < 96; c4 += 4) {
        ushort4 h, l;
        u16* hp = (u16*)&h;
        u16* lp = (u16*)&l;
        for (int j = 0; j < 4; j++) {
            int c = c4 + j;
            float v = (c < 80) ? ldx(x, F, src + c) : 0.f;
            u16 hb = f2b(v);
            hp[j] = hb;
            lp[j] = f2b(v - b2f(hb));
        }
        *(ushort4*)&row[c4] = h;
        *(ushort4*)&row[96 + c4] = l;
    }
}

// ---------------------------------------------------------------- ye scatter
// writes bf16 ye into D1 cols[64,192), D2 cols[512,640), D3 cols[512,640)
__global__ void ye_kernel(const int* __restrict__ y, int b0,
                          const float* __restrict__ spk_n,
                          bf16* __restrict__ D1, bf16* __restrict__ D2,
                          bf16* __restrict__ D3) {
    int b = blockIdx.y;
    int t = blockIdx.x * 256 + threadIdx.x;
    int idx = y[(size_t)(b0 + b) * T_LEN + t];
    const float* s = spk_n + (size_t)idx * 128;
    size_t r = (size_t)b * T_LEN + t;
    u16* p1 = (u16*)D1 + r * 192 + 64;
    u16* p2 = (u16*)D2 + r * 640 + 512;
    u16* p3 = (u16*)D3 + r * 640 + 512;
    for (int d4 = 0; d4 < 128; d4 += 4) {
        float4 v = *(const float4*)&s[d4];
        ushort4 h;
        h.x = f2b(v.x); h.y = f2b(v.y); h.z = f2b(v.z); h.w = f2b(v.w);
        *(ushort4*)&p1[d4] = h;
        *(ushort4*)&p2[d4] = h;
        *(ushort4*)&p3[d4] = h;
    }
}

// ---------------------------------------------------------------- MFMA conv
// Implicit GEMM: out[t][oc] = bias[oc] + sum_{ic,k} W[oc][ic][k] * A[t+k-PAD][ic]
// A: bf16 activation rows [b][t][RS], hi at col 0, optional lo at col loOff.
// W: repacked [K][ocp][Cinp] bf16 (hi; optional lo plane).
// Block: 128 t x 64 oc; 4 waves, each 32 t x 64 oc (2x4 16x16x32 frags).
// aloMode: 0 never, 1 always, 2 iff flag==0. wloMode: 0 never, 2 iff flag==0.
// odt: 0 f32, 1 bf16, 2 external(flag). oRS: out row stride. ocMax: col mask.
template <int KK>
__global__ __launch_bounds__(256) void conv_mfma(
    const int* __restrict__ dflag,
    const bf16* __restrict__ act, int RS, int loOff, int aloMode, int Cinp,
    const bf16* __restrict__ whi, const bf16* __restrict__ wlo, int wloMode,
    const void* __restrict__ bias,
    void* __restrict__ outp, int odt, int oRS, int ocMax, int boff) {
    constexpr int PAD = (KK - 1) / 2;
    constexpr int SROWS = 128 + KK - 1;
    const int F = *dflag;
    const bool useALo = (aloMode == 1) || (aloMode == 2 && F == 0);
    const bool useWLo = (wloMode == 2 && F == 0) && (wlo != nullptr);
    const int ocp = gridDim.y << 6;
    const int t0 = blockIdx.x * 128;
    const int oc0 = blockIdx.y * 64;
    const int b = blockIdx.z;
    const int tid = threadIdx.x;
    const int lane = tid & 63;
    const int wid = tid >> 6;
    const int l16 = lane & 15;
    const int q8 = (lane >> 4) * 8;
    const int quad = lane >> 4;

    __shared__ __align__(16) bf16 sA[2 * SROWS * 40];
    __shared__ __align__(16) bf16 sB[KK * 64 * 40];

    f32x4 acc[2][4];
#pragma unroll
    for (int i = 0; i < 2; i++)
#pragma unroll
        for (int j = 0; j < 4; j++) acc[i][j] = (f32x4){0.f, 0.f, 0.f, 0.f};

    const int nch = Cinp >> 5;
    for (int ch = 0; ch < nch; ch++) {
        const int ic0 = ch << 5;
        // ---- stage A tile (hi [+ lo]), rows t0-PAD .. t0+127+PAD
        for (int g = tid; g < SROWS * 8; g += 256) {
            int row = g >> 3, c4 = (g & 7) << 2;
            int t = t0 - PAD + row;
            ushort4 v = make_ushort4(0, 0, 0, 0);
            ushort4 vl = make_ushort4(0, 0, 0, 0);
            if (t >= 0 && t < T_LEN) {
                const u16* src = (const u16*)act + ((size_t)b * T_LEN + t) * RS + ic0 + c4;
                v = *(const ushort4*)src;
                if (useALo) vl = *(const ushort4*)(src + loOff);
            }
            *(ushort4*)&sA[row * 40 + c4] = v;
            if (useALo) *(ushort4*)&sA[(SROWS + row) * 40 + c4] = vl;
        }
        // ---- stage W tile (hi): KK taps x 64 oc x 32 ic
        for (int g = tid; g < KK * 512; g += 256) {
            int tap = g >> 9;
            int rr = g & 511;
            int ocr = rr >> 3, c4 = (rr & 7) << 2;
            const u16* src = (const u16*)whi +
                             ((size_t)tap * ocp + oc0 + ocr) * Cinp + ic0 + c4;
            *(ushort4*)&sB[(tap * 64 + ocr) * 40 + c4] = *(const ushort4*)src;
        }
        __syncthreads();

#pragma unroll
        for (int tap = 0; tap < KK; tap++) {
            s16x8 bfr[4];
#pragma unroll
            for (int ni = 0; ni < 4; ni++)
                bfr[ni] = *(const s16x8*)&sB[(tap * 64 + ni * 16 + l16) * 40 + q8];
#pragma unroll
            for (int mi = 0; mi < 2; mi++) {
                int row = wid * 32 + mi * 16 + l16 + tap;
                s16x8 a = *(const s16x8*)&sA[row * 40 + q8];
#pragma unroll
                for (int ni = 0; ni < 4; ni++)
                    acc[mi][ni] = __builtin_amdgcn_mfma_f32_16x16x32_bf16(
                        a, bfr[ni], acc[mi][ni], 0, 0, 0);
                if (useALo) {
                    s16x8 al = *(const s16x8*)&sA[(SROWS + row) * 40 + q8];
#pragma unroll
                    for (int ni = 0; ni < 4; ni++)
                        acc[mi][ni] = __builtin_amdgcn_mfma_f32_16x16x32_bf16(
                            al, bfr[ni], acc[mi][ni], 0, 0, 0);
                }
            }
        }
        if (useWLo) {
            __syncthreads();
            for (int g = tid; g < KK * 512; g += 256) {
                int tap = g >> 9;
                int rr = g & 511;
                int ocr = rr >> 3, c4 = (rr & 7) << 2;
                const u16* src = (const u16*)wlo +
                                 ((size_t)tap * ocp + oc0 + ocr) * Cinp + ic0 + c4;
                *(ushort4*)&sB[(tap * 64 + ocr) * 40 + c4] = *(const ushort4*)src;
            }
            __syncthreads();
#pragma unroll
            for (int tap = 0; tap < KK; tap++) {
                s16x8 bfr[4];
#pragma unroll
                for (int ni = 0; ni < 4; ni++)
                    bfr[ni] = *(const s16x8*)&sB[(tap * 64 + ni * 16 + l16) * 40 + q8];
#pragma unroll
                for (int mi = 0; mi < 2; mi++) {
                    int row = wid * 32 + mi * 16 + l16 + tap;
                    s16x8 a = *(const s16x8*)&sA[row * 40 + q8];
#pragma unroll
                    for (int ni = 0; ni < 4; ni++)
                        acc[mi][ni] = __builtin_amdgcn_mfma_f32_16x16x32_bf16(
                            a, bfr[ni], acc[mi][ni], 0, 0, 0);
                }
            }
        }
        __syncthreads();
    }

    // ---- epilogue: D[m=quad*4+r][n=l16] per frag
#pragma unroll
    for (int ni = 0; ni < 4; ni++) {
        int oc = oc0 + ni * 16 + l16;
        if (oc >= ocMax) continue;
        float bv = ldx(bias, F, oc);
#pragma unroll
        for (int mi = 0; mi < 2; mi++) {
#pragma unroll
            for (int r = 0; r < 4; r++) {
                int t = t0 + wid * 32 + mi * 16 + quad * 4 + r;
                float v = acc[mi][ni][r] + bv;
                size_t off = ((size_t)(b + boff) * T_LEN + t) * (size_t)oRS + oc;
                if (odt == 0) ((float*)outp)[off] = v;
                else if (odt == 1) ((bf16*)outp)[off] = __float2bfloat16(v);
                else stx(outp, F, off, v);
            }
        }
    }
}

// ---------------------------------------------------------------- LN + LeakyReLU
// in: F f32 [b][t][512]; out: E bf16 pair [b][t][1024] (hi 0..512, lo 512..1024)
__global__ __launch_bounds__(256) void ln_lrelu(
    const int* __restrict__ dflag, const float* __restrict__ Fin,
    bf16* __restrict__ E, const void* __restrict__ g, const void* __restrict__ bt) {
    const int Fl = *dflag;
    int b = blockIdx.y;
    int t = blockIdx.x * 4 + (threadIdx.x >> 6);
    int lane = threadIdx.x & 63;
    const float* row = Fin + ((size_t)b * T_LEN + t) * 512 + lane * 8;
    float vv[8];
    *(float4*)&vv[0] = *(const float4*)row;
    *(float4*)&vv[4] = *(const float4*)(row + 4);
    float s = 0.f, s2 = 0.f;
#pragma unroll
    for (int j = 0; j < 8; j++) { s += vv[j]; s2 += vv[j] * vv[j]; }
    for (int m = 32; m; m >>= 1) {
        s += __shfl_xor(s, m);
        s2 += __shfl_xor(s2, m);
    }
    float mean = s / 512.f;
    float var = s2 / 512.f - mean * mean;
    float rstd = rsqrtf(var + 1e-5f);
    u16* eo = (u16*)E + ((size_t)b * T_LEN + t) * 1024 + lane * 8;
    ushort4 h[2], l[2];
#pragma unroll
    for (int j = 0; j < 8; j++) {
        int c = lane * 8 + j;
        float v = (vv[j] - mean) * rstd * ldx(g, Fl, c) + ldx(bt, Fl, c);
        v = v >= 0.f ? v : 0.2f * v;
        u16 hb = f2b(v);
        ((u16*)h)[j] = hb;
        ((u16*)l)[j] = f2b(v - b2f(hb));
    }
    *(ushort4*)&eo[0] = h[0];
    *(ushort4*)&eo[4] = h[1];
    *(ushort4*)&eo[512] = l[0];
    *(ushort4*)&eo[516] = l[1];
}

// ---------------------------------------------------------------- LN + GLU
// in: F bf16 [b][t][1024]; out: D bf16 cols [0,512) of rows with stride oRS
__global__ __launch_bounds__(256) void ln_glu(
    const int* __restrict__ dflag, const bf16* __restrict__ Fin,
    bf16* __restrict__ D, int oRS, const void* __restrict__ g,
    const void* __restrict__ bt) {
    const int Fl = *dflag;
    int b = blockIdx.y;
    int t = blockIdx.x * 4 + (threadIdx.x >> 6);
    int lane = threadIdx.x & 63;
    const u16* row = (const u16*)Fin + ((size_t)b * T_LEN + t) * 1024;
    ushort4 ua[2], ug[2];
    ua[0] = *(const ushort4*)&row[lane * 8];
    ua[1] = *(const ushort4*)&row[lane * 8 + 4];
    ug[0] = *(const ushort4*)&row[512 + lane * 8];
    ug[1] = *(const ushort4*)&row[512 + lane * 8 + 4];
    float av[8], gv[8];
#pragma unroll
    for (int j = 0; j < 8; j++) {
        av[j] = b2f(((u16*)ua)[j]);
        gv[j] = b2f(((u16*)ug)[j]);
    }
    float s = 0.f, s2 = 0.f;
#pragma unroll
    for (int j = 0; j < 8; j++) {
        s += av[j] + gv[j];
        s2 += av[j] * av[j] + gv[j] * gv[j];
    }
    for (int m = 32; m; m >>= 1) {
        s += __shfl_xor(s, m);
        s2 += __shfl_xor(s2, m);
    }
    float mean = s / 1024.f;
    float var = s2 / 1024.f - mean * mean;
    float rstd = rsqrtf(var + 1e-5f);
    ushort4 o[2];
#pragma unroll
    for (int j = 0; j < 8; j++) {
        int c = lane * 8 + j;
        float a = (av[j] - mean) * rstd * ldx(g, Fl, c) + ldx(bt, Fl, c);
        float gg = (gv[j] - mean) * rstd * ldx(g, Fl, 512 + c) + ldx(bt, Fl, 512 + c);
        ((u16*)o)[j] = f2b(a / (1.f + expf(-gg)));
    }
    u16* op = (u16*)D + ((size_t)b * T_LEN + t) * oRS + lane * 8;
    *(ushort4*)&op[0] = o[0];
    *(ushort4*)&op[4] = o[1];
}

// ---------------------------------------------------------------- VQ
// z: f32 [b][t][64]; writes bf16 codebook row into D1 cols [0,64)
__global__ __launch_bounds__(256) void vq_kernel(
    const int* __restrict__ dflag, const float* __restrict__ z,
    const void* __restrict__ cb, bf16* __restrict__ D1) {
    const int F = *dflag;
    int b = blockIdx.y;
    int t = blockIdx.x * 256 + threadIdx.x;
    int tid = threadIdx.x;

    __shared__ float sCB[128 * 64];
    __shared__ float sCC[128];

    float zr[64];
    const float* zp = z + ((size_t)b * T_LEN + t) * 64;
#pragma unroll
    for (int d4 = 0; d4 < 64; d4 += 4) *(float4*)&zr[d4] = *(const float4*)&zp[d4];
    float zz = 0.f;
#pragma unroll
    for (int d = 0; d < 64; d++) zz += zr[d] * zr[d];

    float best = 3.4e38f;
    int bidx = 0;
    for (int chunk = 0; chunk < 4; chunk++) {
        __syncthreads();
        for (int i = tid; i < 8192; i += 256)
            sCB[i] = ldx(cb, F, (size_t)chunk * 8192 + i);
        __syncthreads();
        if (tid < 128) {
            float cc = 0.f;
#pragma unroll 8
            for (int d = 0; d < 64; d++) {
                float cv = sCB[tid * 64 + d];
                cc += cv * cv;
            }
            sCC[tid] = cc;
        }
        __syncthreads();
        for (int c = 0; c < 128; c++) {
            const float* cp = &sCB[c * 64];
            float dot = 0.f;
#pragma unroll
            for (int d = 0; d < 64; d++) dot += zr[d] * cp[d];
            float dist = zz + sCC[c] - 2.f * dot;
            if (dist < best) { best = dist; bidx = chunk * 128 + c; }
        }
    }
    u16* out = (u16*)D1 + ((size_t)b * T_LEN + t) * 192;
    for (int d4 = 0; d4 < 64; d4 += 4) {
        ushort4 h;
        h.x = f2b(ldx(cb, F, (size_t)bidx * 64 + d4));
        h.y = f2b(ldx(cb, F, (size_t)bidx * 64 + d4 + 1));
        h.z = f2b(ldx(cb, F, (size_t)bidx * 64 + d4 + 2));
        h.w = f2b(ldx(cb, F, (size_t)bidx * 64 + d4 + 3));
        *(ushort4*)&out[d4] = h;
    }
}

// ---------------------------------------------------------------- launch
extern "C" void kernel_launch(void* const* d_in, const int* in_sizes, int n_in,
                              void* d_out, int out_size, void* d_ws,
                              size_t ws_size, hipStream_t stream) {
    const void* x = d_in[0];
    const int* y = (const int*)d_in[1];
    const void* enc_w1 = d_in[2];  const void* enc_b1 = d_in[3];
    const void* enc_g1 = d_in[4];  const void* enc_bt1 = d_in[5];
    const void* enc_w2 = d_in[6];  const void* enc_b2 = d_in[7];
    const void* enc_g2 = d_in[8];  const void* enc_bt2 = d_in[9];
    const void* enc_w3 = d_in[10]; const void* enc_b3 = d_in[11];
    const void* enc_g3 = d_in[12]; const void* enc_bt3 = d_in[13];
    const void* mlp_w = d_in[14];  const void* mlp_b = d_in[15];
    const void* codebook = d_in[16];
    const void* spk_emb = d_in[17];
    const void* dec_w1 = d_in[18]; const void* dec_b1 = d_in[19];
    const void* dec_g1 = d_in[20]; const void* dec_bt1 = d_in[21];
    const void* dec_w2 = d_in[22]; const void* dec_b2 = d_in[23];
    const void* dec_g2 = d_in[24]; const void* dec_bt2 = d_in[25];
    const void* dec_w3 = d_in[26]; const void* dec_b3 = d_in[27];

    // weight repack sizes (elements)
    const size_t SW1 = (size_t)5 * 512 * 96;
    const size_t SW2 = (size_t)5 * 512 * 512;
    const size_t SW3 = SW2;
    const size_t SWM = (size_t)64 * 512;
    const size_t SD1 = (size_t)5 * 1024 * 192;
    const size_t SD2 = (size_t)5 * 1024 * 640;
    const size_t SD3 = (size_t)5 * 128 * 640;
    const size_t HI_TOT = SW1 + SW2 + SW3 + SWM + SD1 + SD2 + SD3;
    const size_t LO_TOT = SW1 + SW2 + SW3 + SWM;

    // per-batch activation bytes: xp/D1 + E + F + zbuf + D2 + D3
    const size_t PB = (size_t)T_LEN * (192 * 2 + 1024 * 2 + 2048 + 64 * 4 + 640 * 2 + 640 * 2);
    const size_t FIXED = 256 + 65536 + (HI_TOT + LO_TOT) * 2;

    int nb = BATCH;
    while (nb > 1 && FIXED + (size_t)nb * PB > ws_size) nb >>= 1;

    char* p = (char*)d_ws;
    int* dflag = (int*)p;        p += 256;
    float* spk_n = (float*)p;    p += 65536;
    bf16* w1h = (bf16*)p;        p += SW1 * 2;
    bf16* w2h = (bf16*)p;        p += SW2 * 2;
    bf16* w3h = (bf16*)p;        p += SW3 * 2;
    bf16* wmh = (bf16*)p;        p += SWM * 2;
    bf16* wd1 = (bf16*)p;        p += SD1 * 2;
    bf16* wd2 = (bf16*)p;        p += SD2 * 2;
    bf16* wd3 = (bf16*)p;        p += SD3 * 2;
    bf16* w1l = (bf16*)p;        p += SW1 * 2;
    bf16* w2l = (bf16*)p;        p += SW2 * 2;
    bf16* w3l = (bf16*)p;        p += SW3 * 2;
    bf16* wml = (bf16*)p;        p += SWM * 2;
    bf16* xp = (bf16*)p;         p += (size_t)nb * T_LEN * 192 * 2;  // aliases D1
    bf16* E = (bf16*)p;          p += (size_t)nb * T_LEN * 1024 * 2;
    char* Fb = p;                p += (size_t)nb * T_LEN * 2048;     // f32x512 / bf16x1024
    float* zbuf = (float*)p;     p += (size_t)nb * T_LEN * 64 * 4;
    bf16* D2 = (bf16*)p;         p += (size_t)nb * T_LEN * 640 * 2;
    bf16* D3 = (bf16*)p;
    bf16* D1 = xp;
    float* Ff = (float*)Fb;
    bf16* Fh = (bf16*)Fb;

    dim3 blk(256);

    detect_kernel<<<1, 256, 0, stream>>>((const float*)x, dflag);
    spk_norm_kernel<<<128, 128, 0, stream>>>(dflag, spk_emb, spk_n);

    // repack weights (once per call)
    repack_kernel<<<2048, blk, 0, stream>>>(dflag, enc_w1, 0, 512, 80, 5, 512, 96, w1h, w1l);
    repack_kernel<<<2048, blk, 0, stream>>>(dflag, enc_w2, 0, 512, 512, 5, 512, 512, w2h, w2l);
    repack_kernel<<<2048, blk, 0, stream>>>(dflag, enc_w3, 0, 512, 512, 5, 512, 512, w3h, w3l);
    repack_kernel<<<2048, blk, 0, stream>>>(dflag, mlp_w, 0, 64, 512, 1, 64, 512, wmh, wml);
    repack_kernel<<<2048, blk, 0, stream>>>(dflag, dec_w1, 1, 1024, 192, 5, 1024, 192, wd1, nullptr);
    repack_kernel<<<2048, blk, 0, stream>>>(dflag, dec_w2, 1, 1024, 640, 5, 1024, 640, wd2, nullptr);
    repack_kernel<<<2048, blk, 0, stream>>>(dflag, dec_w3, 1, 80, 640, 5, 128, 640, wd3, nullptr);

    for (int b0 = 0; b0 < BATCH; b0 += nb) {
        dim3 gT(T_LEN / 256, nb);
        dim3 gLN(T_LEN / 4, nb);

        xprep_kernel<<<gT, blk, 0, stream>>>(dflag, x, b0, xp);

        // encoder
        conv_mfma<5><<<dim3(32, 8, nb), blk, 0, stream>>>(
            dflag, xp, 192, 96, 2, 96, w1h, w1l, 2, enc_b1, Ff, 0, 512, 512, 0);
        // ye written after enc1 consumed xp (D1 aliases xp)
        ye_kernel<<<gT, blk, 0, stream>>>(y, b0, spk_n, D1, D2, D3);
        ln_lrelu<<<gLN, blk, 0, stream>>>(dflag, Ff, E, enc_g1, enc_bt1);
        conv_mfma<5><<<dim3(32, 8, nb), blk, 0, stream>>>(
            dflag, E, 1024, 512, 1, 512, w2h, w2l, 2, enc_b2, Ff, 0, 512, 512, 0);
        ln_lrelu<<<gLN, blk, 0, stream>>>(dflag, Ff, E, enc_g2, enc_bt2);
        conv_mfma<5><<<dim3(32, 8, nb), blk, 0, stream>>>(
            dflag, E, 1024, 512, 1, 512, w3h, w3l, 2, enc_b3, Ff, 0, 512, 512, 0);
        ln_lrelu<<<gLN, blk, 0, stream>>>(dflag, Ff, E, enc_g3, enc_bt3);

        // 1x1 conv to z
        conv_mfma<1><<<dim3(32, 1, nb), blk, 0, stream>>>(
            dflag, E, 1024, 512, 1, 512, wmh, wml, 2, mlp_b, zbuf, 0, 64, 64, 0);

        // vector quantize -> D1 cols [0,64)
        vq_kernel<<<gT, blk, 0, stream>>>(dflag, zbuf, codebook, D1);

        // decoder
        conv_mfma<5><<<dim3(32, 16, nb), blk, 0, stream>>>(
            dflag, D1, 192, 0, 0, 192, wd1, nullptr, 0, dec_b1, Fh, 1, 1024, 1024, 0);
        ln_glu<<<gLN, blk, 0, stream>>>(dflag, Fh, D2, 640, dec_g1, dec_bt1);
        conv_mfma<5><<<dim3(32, 16, nb), blk, 0, stream>>>(
            dflag, D2, 640, 0, 0, 640, wd2, nullptr, 0, dec_b2, Fh, 1, 1024, 1024, 0);
        ln_glu<<<gLN, blk, 0, stream>>>(dflag, Fh, D3, 640, dec_g2, dec_bt2);
        conv_mfma<5><<<dim3(32, 2, nb), blk, 0, stream>>>(
            dflag, D3, 640, 0, 0, 640, wd3, nullptr, 0, dec_b3, d_out, 2, 80, 80, b0);
    }
}

// Round 5
// 4927.522 us; speedup vs baseline: 4.3549x; 1.1376x over previous
//
#include <hip/hip_runtime.h>
#include <hip/hip_bf16.h>
#include <cmath>

#define T_LEN 4096
#define BATCH 16
typedef __hip_bfloat16 bf16;
typedef unsigned short u16;
typedef float f32x4 __attribute__((ext_vector_type(4)));
typedef short s16x8 __attribute__((ext_vector_type(8)));
typedef unsigned short u16x8 __attribute__((ext_vector_type(8)));

__device__ __forceinline__ float ldx(const void* p, int dt, size_t i) {
    return dt ? __bfloat162float(((const bf16*)p)[i]) : ((const float*)p)[i];
}
__device__ __forceinline__ void stx(void* p, int dt, size_t i, float v) {
    if (dt) ((bf16*)p)[i] = __float2bfloat16(v);
    else ((float*)p)[i] = v;
}
__device__ __forceinline__ u16 f2b(float v) {
    bf16 h = __float2bfloat16(v);
    return *(u16*)&h;
}
__device__ __forceinline__ float b2f(u16 u) {
    return __bfloat162float(*(const bf16*)&u);
}

// ---------------------------------------------------------------- dtype probe
__global__ void detect_kernel(const float* __restrict__ x, int* __restrict__ flag) {
    __shared__ int s[256];
    int tid = threadIdx.x;
    int bad = 0;
    for (int i = tid; i < 2048; i += 256) {
        float v = x[i];
        if (!(fabsf(v) < 1e30f)) bad = 1;
    }
    s[tid] = bad;
    __syncthreads();
    for (int off = 128; off > 0; off >>= 1) {
        if (tid < off) s[tid] |= s[tid + off];
        __syncthreads();
    }
    if (tid == 0) *flag = s[0];
}

// ---------------------------------------------------------------- spk norm
__global__ void spk_norm_kernel(const int* __restrict__ dflag,
                                const void* __restrict__ spk,
                                float* __restrict__ out) {
    const int f = *dflag;
    int s = blockIdx.x, d = threadIdx.x;
    float v = ldx(spk, f, (size_t)s * 128 + d);
    __shared__ float red[128];
    red[d] = v * v;
    __syncthreads();
    for (int off = 64; off > 0; off >>= 1) {
        if (d < off) red[d] += red[d + off];
        __syncthreads();
    }
    float rs = rsqrtf(red[0]);
    out[s * 128 + d] = v * rs;
}

// ---------------------------------------------------------------- weight repack (coalesced, LDS transpose)
// dst: [K][ocp][Cinp] bf16, zero-padded. Max K = 5.
// wmode0: src [Cout][Cin][K]; tile 64 oc x 32 ic.
__global__ __launch_bounds__(256) void repack0_kernel(
    const int* __restrict__ dflag, const void* __restrict__ src,
    int Cout, int Cin, int K, int ocp, int Cinp,
    bf16* __restrict__ dsthi, bf16* __restrict__ dstlo) {
    const int F = *dflag;
    __shared__ u16 sh[64 * 32 * 5];
    __shared__ u16 sl[64 * 32 * 5];
    const int ic0 = blockIdx.x * 32;
    const int oc0 = blockIdx.y * 64;
    const int tid = threadIdx.x;
    const int N = 64 * 32 * K;
    for (int idx = tid; idx < N; idx += 256) {
        int ocl = idx / (32 * K);
        int r = idx % (32 * K);
        int icl = r / K, k = r % K;
        int oc = oc0 + ocl, ic = ic0 + icl;
        float v = 0.f;
        if (oc < Cout && ic < Cin)
            v = ldx(src, F, ((size_t)oc * Cin + ic) * K + k);
        u16 hb = f2b(v);
        sh[(ocl * 32 + icl) * K + k] = hb;
        sl[(ocl * 32 + icl) * K + k] = f2b(v - b2f(hb));
    }
    __syncthreads();
    const int M = K * 64 * 4;  // units of 8 ic
    for (int idx = tid; idx < M; idx += 256) {
        int k = idx / (64 * 4);
        int r = idx % (64 * 4);
        int ocl = r >> 2;
        int g8 = (r & 3) << 3;
        u16x8 h, l;
#pragma unroll
        for (int j = 0; j < 8; j++) {
            h[j] = sh[(ocl * 32 + g8 + j) * K + k];
            l[j] = sl[(ocl * 32 + g8 + j) * K + k];
        }
        size_t off = ((size_t)k * ocp + oc0 + ocl) * Cinp + ic0 + g8;
        *(u16x8*)&dsthi[off] = h;
        if (dstlo) *(u16x8*)&dstlo[off] = l;
    }
}

// wmode1 (convT): src [Cin][Cout][K]; W_eff[o][i][k]=src[i][o][K-1-k]; tile 64 ic x 32 oc.
__global__ __launch_bounds__(256) void repack1_kernel(
    const int* __restrict__ dflag, const void* __restrict__ src,
    int Cout, int Cin, int K, int ocp, int Cinp,
    bf16* __restrict__ dsthi) {
    const int F = *dflag;
    __shared__ u16 sh[64 * 32 * 5];
    const int ic0 = blockIdx.x * 64;
    const int oc0 = blockIdx.y * 32;
    const int tid = threadIdx.x;
    const int N = 64 * 32 * K;
    for (int idx = tid; idx < N; idx += 256) {
        int icl = idx / (32 * K);
        int r = idx % (32 * K);
        int ocl = r / K, k = r % K;
        int oc = oc0 + ocl, ic = ic0 + icl;
        float v = 0.f;
        if (oc < Cout && ic < Cin)
            v = ldx(src, F, ((size_t)ic * Cout + oc) * K + k);
        sh[(icl * 32 + ocl) * K + (K - 1 - k)] = f2b(v);
    }
    __syncthreads();
    const int M = K * 32 * 8;  // units of 8 ic
    for (int idx = tid; idx < M; idx += 256) {
        int k = idx / (32 * 8);
        int r = idx % (32 * 8);
        int ocl = r >> 3;
        int g8 = (r & 7) << 3;
        u16x8 h;
#pragma unroll
        for (int j = 0; j < 8; j++)
            h[j] = sh[((g8 + j) * 32 + ocl) * K + k];
        size_t off = ((size_t)k * ocp + oc0 + ocl) * Cinp + ic0 + g8;
        *(u16x8*)&dsthi[off] = h;
    }
}

// ---------------------------------------------------------------- x prep
// x external [b_abs][t][80] -> xp [b][t][192]: hi [0,96) (pad 0), lo [96,192)
__global__ void xprep_kernel(const int* __restrict__ dflag,
                             const void* __restrict__ x, int b0,
                             bf16* __restrict__ xp) {
    const int F = *dflag;
    int b = blockIdx.y;
    int t = blockIdx.x * 256 + threadIdx.x;
    size_t src = ((size_t)(b0 + b) * T_LEN + t) * 80;
    u16* row = (u16*)xp + ((size_t)b * T_LEN + t) * 192;
    for (int c4 = 0; c4 < 96; c4 += 4) {
        ushort4 h, l;
        u16* hp = (u16*)&h;
        u16* lp = (u16*)&l;
        for (int j = 0; j < 4; j++) {
            int c = c4 + j;
            float v = (c < 80) ? ldx(x, F, src + c) : 0.f;
            u16 hb = f2b(v);
            hp[j] = hb;
            lp[j] = f2b(v - b2f(hb));
        }
        *(ushort4*)&row[c4] = h;
        *(ushort4*)&row[96 + c4] = l;
    }
}

// ---------------------------------------------------------------- ye scatter
__global__ void ye_kernel(const int* __restrict__ y, int b0,
                          const float* __restrict__ spk_n,
                          bf16* __restrict__ D1, bf16* __restrict__ D2,
                          bf16* __restrict__ D3) {
    int b = blockIdx.y;
    int t = blockIdx.x * 256 + threadIdx.x;
    int idx = y[(size_t)(b0 + b) * T_LEN + t];
    const float* s = spk_n + (size_t)idx * 128;
    size_t r = (size_t)b * T_LEN + t;
    u16* p1 = (u16*)D1 + r * 192 + 64;
    u16* p2 = (u16*)D2 + r * 640 + 512;
    u16* p3 = (u16*)D3 + r * 640 + 512;
    for (int d4 = 0; d4 < 128; d4 += 4) {
        float4 v = *(const float4*)&s[d4];
        ushort4 h;
        h.x = f2b(v.x); h.y = f2b(v.y); h.z = f2b(v.z); h.w = f2b(v.w);
        *(ushort4*)&p1[d4] = h;
        *(ushort4*)&p2[d4] = h;
        *(ushort4*)&p3[d4] = h;
    }
}

// ---------------------------------------------------------------- MFMA conv
// Implicit GEMM: out[t][oc] = bias[oc] + sum_{ic,k} W[oc][ic][k] * A[t+k-PAD][ic]
// Block 128t x 128oc; 4 waves in 2x2; wave tile 64t x 64oc (4x4 16x16x32 frags).
// A: bf16 rows [b][t][RS], hi at col 0, optional lo at col loOff.
// W: repacked [K][ocp][Cinp] bf16 (ocp = gridDim.y*128).
// aloMode: 0 never, 1 always, 2 iff flag==0. wloMode: 0 never, 2 iff flag==0.
template <int KK>
__global__ __launch_bounds__(256) void conv_mfma(
    const int* __restrict__ dflag,
    const bf16* __restrict__ act, int RS, int loOff, int aloMode, int Cinp,
    const bf16* __restrict__ whi, const bf16* __restrict__ wlo, int wloMode,
    const void* __restrict__ bias,
    void* __restrict__ outp, int odt, int oRS, int ocMax, int boff) {
    constexpr int PAD = (KK - 1) / 2;
    constexpr int SROWS = 128 + KK - 1;
    const int F = *dflag;
    const bool useALo = (aloMode == 1) || (aloMode == 2 && F == 0);
    const bool useWLo = (wloMode == 2 && F == 0) && (wlo != nullptr);
    const int ocp = gridDim.y << 7;
    const int t0 = blockIdx.x * 128;
    const int oc0 = blockIdx.y * 128;
    const int b = blockIdx.z;
    const int tid = threadIdx.x;
    const int lane = tid & 63;
    const int wid = tid >> 6;
    const int widT = wid >> 1;       // 0..1 t half
    const int widN = wid & 1;        // 0..1 oc half
    const int l16 = lane & 15;
    const int quad = lane >> 4;
    const int q8 = quad * 8;

    __shared__ __align__(16) bf16 sA[2 * SROWS * 40];
    __shared__ __align__(16) bf16 sB[KK * 128 * 40];

    f32x4 acc[4][4];
#pragma unroll
    for (int i = 0; i < 4; i++)
#pragma unroll
        for (int j = 0; j < 4; j++) acc[i][j] = (f32x4){0.f, 0.f, 0.f, 0.f};

    const int nch = Cinp >> 5;
    for (int ch = 0; ch < nch; ch++) {
        const int ic0 = ch << 5;
        // ---- stage A tile (hi [+ lo]) rows t0-PAD..t0+127+PAD, 16B units
        for (int g = tid; g < SROWS * 4; g += 256) {
            int row = g >> 2, c8 = (g & 3) << 3;
            int t = t0 - PAD + row;
            u16x8 v = (u16x8){0, 0, 0, 0, 0, 0, 0, 0};
            u16x8 vl = (u16x8){0, 0, 0, 0, 0, 0, 0, 0};
            if (t >= 0 && t < T_LEN) {
                const u16* src = (const u16*)act + ((size_t)b * T_LEN + t) * RS + ic0 + c8;
                v = *(const u16x8*)src;
                if (useALo) vl = *(const u16x8*)(src + loOff);
            }
            *(u16x8*)&sA[row * 40 + c8] = v;
            if (useALo) *(u16x8*)&sA[(SROWS + row) * 40 + c8] = vl;
        }
        // ---- stage W tile (hi): KK taps x 128 oc x 32 ic
        for (int g = tid; g < KK * 512; g += 256) {
            int tap = g >> 9;
            int r = g & 511;
            int ocr = r >> 2, c8 = (r & 3) << 3;
            const u16* src = (const u16*)whi +
                             ((size_t)tap * ocp + oc0 + ocr) * Cinp + ic0 + c8;
            *(u16x8*)&sB[(tap * 128 + ocr) * 40 + c8] = *(const u16x8*)src;
        }
        __syncthreads();

#pragma unroll
        for (int tap = 0; tap < KK; tap++) {
            s16x8 bfr[4];
#pragma unroll
            for (int ni = 0; ni < 4; ni++)
                bfr[ni] = *(const s16x8*)&sB[(tap * 128 + widN * 64 + ni * 16 + l16) * 40 + q8];
#pragma unroll
            for (int mi = 0; mi < 4; mi++) {
                int row = widT * 64 + mi * 16 + l16 + tap;
                s16x8 a = *(const s16x8*)&sA[row * 40 + q8];
#pragma unroll
                for (int ni = 0; ni < 4; ni++)
                    acc[mi][ni] = __builtin_amdgcn_mfma_f32_16x16x32_bf16(
                        a, bfr[ni], acc[mi][ni], 0, 0, 0);
                if (useALo) {
                    s16x8 al = *(const s16x8*)&sA[(SROWS + row) * 40 + q8];
#pragma unroll
                    for (int ni = 0; ni < 4; ni++)
                        acc[mi][ni] = __builtin_amdgcn_mfma_f32_16x16x32_bf16(
                            al, bfr[ni], acc[mi][ni], 0, 0, 0);
                }
            }
        }
        if (useWLo) {
            __syncthreads();
            for (int g = tid; g < KK * 512; g += 256) {
                int tap = g >> 9;
                int r = g & 511;
                int ocr = r >> 2, c8 = (r & 3) << 3;
                const u16* src = (const u16*)wlo +
                                 ((size_t)tap * ocp + oc0 + ocr) * Cinp + ic0 + c8;
                *(u16x8*)&sB[(tap * 128 + ocr) * 40 + c8] = *(const u16x8*)src;
            }
            __syncthreads();
#pragma unroll
            for (int tap = 0; tap < KK; tap++) {
                s16x8 bfr[4];
#pragma unroll
                for (int ni = 0; ni < 4; ni++)
                    bfr[ni] = *(const s16x8*)&sB[(tap * 128 + widN * 64 + ni * 16 + l16) * 40 + q8];
#pragma unroll
                for (int mi = 0; mi < 4; mi++) {
                    int row = widT * 64 + mi * 16 + l16 + tap;
                    s16x8 a = *(const s16x8*)&sA[row * 40 + q8];
#pragma unroll
                    for (int ni = 0; ni < 4; ni++)
                        acc[mi][ni] = __builtin_amdgcn_mfma_f32_16x16x32_bf16(
                            a, bfr[ni], acc[mi][ni], 0, 0, 0);
                }
            }
        }
        __syncthreads();
    }

    // ---- epilogue: D row = quad*4+r (t), col = l16 (oc)
#pragma unroll
    for (int ni = 0; ni < 4; ni++) {
        int oc = oc0 + widN * 64 + ni * 16 + l16;
        if (oc >= ocMax) continue;
        float bv = ldx(bias, F, oc);
#pragma unroll
        for (int mi = 0; mi < 4; mi++) {
#pragma unroll
            for (int r = 0; r < 4; r++) {
                int t = t0 + widT * 64 + mi * 16 + quad * 4 + r;
                float v = acc[mi][ni][r] + bv;
                size_t off = ((size_t)(b + boff) * T_LEN + t) * (size_t)oRS + oc;
                if (odt == 0) ((float*)outp)[off] = v;
                else if (odt == 1) ((bf16*)outp)[off] = __float2bfloat16(v);
                else stx(outp, F, off, v);
            }
        }
    }
}

// ---------------------------------------------------------------- LN + LeakyReLU
// in: f32 [b][t][512]; out: bf16 pair [b][t][1024] (hi 0..512, lo 512..1024)
__global__ __launch_bounds__(256) void ln_lrelu(
    const int* __restrict__ dflag, const float* __restrict__ Fin,
    bf16* __restrict__ E, const void* __restrict__ g, const void* __restrict__ bt) {
    const int Fl = *dflag;
    int b = blockIdx.y;
    int t = blockIdx.x * 4 + (threadIdx.x >> 6);
    int lane = threadIdx.x & 63;
    const float* row = Fin + ((size_t)b * T_LEN + t) * 512 + lane * 8;
    float vv[8];
    *(float4*)&vv[0] = *(const float4*)row;
    *(float4*)&vv[4] = *(const float4*)(row + 4);
    float s = 0.f, s2 = 0.f;
#pragma unroll
    for (int j = 0; j < 8; j++) { s += vv[j]; s2 += vv[j] * vv[j]; }
    for (int m = 32; m; m >>= 1) {
        s += __shfl_xor(s, m);
        s2 += __shfl_xor(s2, m);
    }
    float mean = s / 512.f;
    float var = s2 / 512.f - mean * mean;
    float rstd = rsqrtf(var + 1e-5f);
    u16* eo = (u16*)E + ((size_t)b * T_LEN + t) * 1024 + lane * 8;
    ushort4 h[2], l[2];
#pragma unroll
    for (int j = 0; j < 8; j++) {
        int c = lane * 8 + j;
        float v = (vv[j] - mean) * rstd * ldx(g, Fl, c) + ldx(bt, Fl, c);
        v = v >= 0.f ? v : 0.2f * v;
        u16 hb = f2b(v);
        ((u16*)h)[j] = hb;
        ((u16*)l)[j] = f2b(v - b2f(hb));
    }
    *(ushort4*)&eo[0] = h[0];
    *(ushort4*)&eo[4] = h[1];
    *(ushort4*)&eo[512] = l[0];
    *(ushort4*)&eo[516] = l[1];
}

// ---------------------------------------------------------------- LN + GLU
__global__ __launch_bounds__(256) void ln_glu(
    const int* __restrict__ dflag, const bf16* __restrict__ Fin,
    bf16* __restrict__ D, int oRS, const void* __restrict__ g,
    const void* __restrict__ bt) {
    const int Fl = *dflag;
    int b = blockIdx.y;
    int t = blockIdx.x * 4 + (threadIdx.x >> 6);
    int lane = threadIdx.x & 63;
    const u16* row = (const u16*)Fin + ((size_t)b * T_LEN + t) * 1024;
    ushort4 ua[2], ug[2];
    ua[0] = *(const ushort4*)&row[lane * 8];
    ua[1] = *(const ushort4*)&row[lane * 8 + 4];
    ug[0] = *(const ushort4*)&row[512 + lane * 8];
    ug[1] = *(const ushort4*)&row[512 + lane * 8 + 4];
    float av[8], gv[8];
#pragma unroll
    for (int j = 0; j < 8; j++) {
        av[j] = b2f(((u16*)ua)[j]);
        gv[j] = b2f(((u16*)ug)[j]);
    }
    float s = 0.f, s2 = 0.f;
#pragma unroll
    for (int j = 0; j < 8; j++) {
        s += av[j] + gv[j];
        s2 += av[j] * av[j] + gv[j] * gv[j];
    }
    for (int m = 32; m; m >>= 1) {
        s += __shfl_xor(s, m);
        s2 += __shfl_xor(s2, m);
    }
    float mean = s / 1024.f;
    float var = s2 / 1024.f - mean * mean;
    float rstd = rsqrtf(var + 1e-5f);
    ushort4 o[2];
#pragma unroll
    for (int j = 0; j < 8; j++) {
        int c = lane * 8 + j;
        float a = (av[j] - mean) * rstd * ldx(g, Fl, c) + ldx(bt, Fl, c);
        float gg = (gv[j] - mean) * rstd * ldx(g, Fl, 512 + c) + ldx(bt, Fl, 512 + c);
        ((u16*)o)[j] = f2b(a / (1.f + expf(-gg)));
    }
    u16* op = (u16*)D + ((size_t)b * T_LEN + t) * oRS + lane * 8;
    *(ushort4*)&op[0] = o[0];
    *(ushort4*)&op[4] = o[1];
}

// ---------------------------------------------------------------- VQ
__global__ __launch_bounds__(256) void vq_kernel(
    const int* __restrict__ dflag, const float* __restrict__ z,
    const void* __restrict__ cb, bf16* __restrict__ D1) {
    const int F = *dflag;
    int b = blockIdx.y;
    int t = blockIdx.x * 256 + threadIdx.x;
    int tid = threadIdx.x;

    __shared__ float sCB[128 * 64];
    __shared__ float sCC[128];

    float zr[64];
    const float* zp = z + ((size_t)b * T_LEN + t) * 64;
#pragma unroll
    for (int d4 = 0; d4 < 64; d4 += 4) *(float4*)&zr[d4] = *(const float4*)&zp[d4];
    float zz = 0.f;
#pragma unroll
    for (int d = 0; d < 64; d++) zz += zr[d] * zr[d];

    float best = 3.4e38f;
    int bidx = 0;
    for (int chunk = 0; chunk < 4; chunk++) {
        __syncthreads();
        for (int i = tid; i < 8192; i += 256)
            sCB[i] = ldx(cb, F, (size_t)chunk * 8192 + i);
        __syncthreads();
        if (tid < 128) {
            float cc = 0.f;
#pragma unroll 8
            for (int d = 0; d < 64; d++) {
                float cv = sCB[tid * 64 + d];
                cc += cv * cv;
            }
            sCC[tid] = cc;
        }
        __syncthreads();
        for (int c = 0; c < 128; c++) {
            const float* cp = &sCB[c * 64];
            float dot = 0.f;
#pragma unroll
            for (int d = 0; d < 64; d++) dot += zr[d] * cp[d];
            float dist = zz + sCC[c] - 2.f * dot;
            if (dist < best) { best = dist; bidx = chunk * 128 + c; }
        }
    }
    u16* out = (u16*)D1 + ((size_t)b * T_LEN + t) * 192;
    for (int d4 = 0; d4 < 64; d4 += 4) {
        ushort4 h;
        h.x = f2b(ldx(cb, F, (size_t)bidx * 64 + d4));
        h.y = f2b(ldx(cb, F, (size_t)bidx * 64 + d4 + 1));
        h.z = f2b(ldx(cb, F, (size_t)bidx * 64 + d4 + 2));
        h.w = f2b(ldx(cb, F, (size_t)bidx * 64 + d4 + 3));
        *(ushort4*)&out[d4] = h;
    }
}

// ---------------------------------------------------------------- launch
extern "C" void kernel_launch(void* const* d_in, const int* in_sizes, int n_in,
                              void* d_out, int out_size, void* d_ws,
                              size_t ws_size, hipStream_t stream) {
    const void* x = d_in[0];
    const int* y = (const int*)d_in[1];
    const void* enc_w1 = d_in[2];  const void* enc_b1 = d_in[3];
    const void* enc_g1 = d_in[4];  const void* enc_bt1 = d_in[5];
    const void* enc_w2 = d_in[6];  const void* enc_b2 = d_in[7];
    const void* enc_g2 = d_in[8];  const void* enc_bt2 = d_in[9];
    const void* enc_w3 = d_in[10]; const void* enc_b3 = d_in[11];
    const void* enc_g3 = d_in[12]; const void* enc_bt3 = d_in[13];
    const void* mlp_w = d_in[14];  const void* mlp_b = d_in[15];
    const void* codebook = d_in[16];
    const void* spk_emb = d_in[17];
    const void* dec_w1 = d_in[18]; const void* dec_b1 = d_in[19];
    const void* dec_g1 = d_in[20]; const void* dec_bt1 = d_in[21];
    const void* dec_w2 = d_in[22]; const void* dec_b2 = d_in[23];
    const void* dec_g2 = d_in[24]; const void* dec_bt2 = d_in[25];
    const void* dec_w3 = d_in[26]; const void* dec_b3 = d_in[27];

    // repacked weight sizes (elements)
    const size_t SW1 = (size_t)5 * 512 * 96;
    const size_t SW2 = (size_t)5 * 512 * 512;
    const size_t SW3 = SW2;
    const size_t SWM = (size_t)128 * 512;
    const size_t SD1 = (size_t)5 * 1024 * 192;
    const size_t SD2 = (size_t)5 * 1024 * 640;
    const size_t SD3 = (size_t)5 * 128 * 640;
    const size_t HI_TOT = SW1 + SW2 + SW3 + SWM + SD1 + SD2 + SD3;
    const size_t LO_TOT = SW1 + SW2 + SW3 + SWM;

    const size_t PB = (size_t)T_LEN * (192 * 2 + 1024 * 2 + 2048 + 64 * 4 + 640 * 2 + 640 * 2);
    const size_t FIXED = 256 + 65536 + (HI_TOT + LO_TOT) * 2;

    int nb = BATCH;
    while (nb > 1 && FIXED + (size_t)nb * PB > ws_size) nb >>= 1;

    char* p = (char*)d_ws;
    int* dflag = (int*)p;        p += 256;
    float* spk_n = (float*)p;    p += 65536;
    bf16* w1h = (bf16*)p;        p += SW1 * 2;
    bf16* w2h = (bf16*)p;        p += SW2 * 2;
    bf16* w3h = (bf16*)p;        p += SW3 * 2;
    bf16* wmh = (bf16*)p;        p += SWM * 2;
    bf16* wd1 = (bf16*)p;        p += SD1 * 2;
    bf16* wd2 = (bf16*)p;        p += SD2 * 2;
    bf16* wd3 = (bf16*)p;        p += SD3 * 2;
    bf16* w1l = (bf16*)p;        p += SW1 * 2;
    bf16* w2l = (bf16*)p;        p += SW2 * 2;
    bf16* w3l = (bf16*)p;        p += SW3 * 2;
    bf16* wml = (bf16*)p;        p += SWM * 2;
    bf16* xp = (bf16*)p;         p += (size_t)nb * T_LEN * 192 * 2;  // aliases D1
    bf16* E = (bf16*)p;          p += (size_t)nb * T_LEN * 1024 * 2;
    char* Fb = p;                p += (size_t)nb * T_LEN * 2048;     // f32x512 / bf16x1024
    float* zbuf = (float*)p;     p += (size_t)nb * T_LEN * 64 * 4;
    bf16* D2 = (bf16*)p;         p += (size_t)nb * T_LEN * 640 * 2;
    bf16* D3 = (bf16*)p;
    bf16* D1 = xp;
    float* Ff = (float*)Fb;
    bf16* Fh = (bf16*)Fb;

    dim3 blk(256);

    detect_kernel<<<1, 256, 0, stream>>>((const float*)x, dflag);
    spk_norm_kernel<<<128, 128, 0, stream>>>(dflag, spk_emb, spk_n);

    // repack weights (coalesced tiles)
    repack0_kernel<<<dim3(3, 8), blk, 0, stream>>>(dflag, enc_w1, 512, 80, 5, 512, 96, w1h, w1l);
    repack0_kernel<<<dim3(16, 8), blk, 0, stream>>>(dflag, enc_w2, 512, 512, 5, 512, 512, w2h, w2l);
    repack0_kernel<<<dim3(16, 8), blk, 0, stream>>>(dflag, enc_w3, 512, 512, 5, 512, 512, w3h, w3l);
    repack0_kernel<<<dim3(16, 2), blk, 0, stream>>>(dflag, mlp_w, 64, 512, 1, 128, 512, wmh, wml);
    repack1_kernel<<<dim3(3, 32), blk, 0, stream>>>(dflag, dec_w1, 1024, 192, 5, 1024, 192, wd1);
    repack1_kernel<<<dim3(10, 32), blk, 0, stream>>>(dflag, dec_w2, 1024, 640, 5, 1024, 640, wd2);
    repack1_kernel<<<dim3(10, 4), blk, 0, stream>>>(dflag, dec_w3, 80, 640, 5, 128, 640, wd3);

    for (int b0 = 0; b0 < BATCH; b0 += nb) {
        dim3 gT(T_LEN / 256, nb);
        dim3 gLN(T_LEN / 4, nb);

        xprep_kernel<<<gT, blk, 0, stream>>>(dflag, x, b0, xp);

        // encoder (f32-pair intermediates)
        conv_mfma<5><<<dim3(32, 4, nb), blk, 0, stream>>>(
            dflag, xp, 192, 96, 2, 96, w1h, w1l, 2, enc_b1, Ff, 0, 512, 512, 0);
        // ye written after enc1 consumed xp (D1 aliases xp)
        ye_kernel<<<gT, blk, 0, stream>>>(y, b0, spk_n, D1, D2, D3);
        ln_lrelu<<<gLN, blk, 0, stream>>>(dflag, Ff, E, enc_g1, enc_bt1);
        conv_mfma<5><<<dim3(32, 4, nb), blk, 0, stream>>>(
            dflag, E, 1024, 512, 1, 512, w2h, w2l, 2, enc_b2, Ff, 0, 512, 512, 0);
        ln_lrelu<<<gLN, blk, 0, stream>>>(dflag, Ff, E, enc_g2, enc_bt2);
        conv_mfma<5><<<dim3(32, 4, nb), blk, 0, stream>>>(
            dflag, E, 1024, 512, 1, 512, w3h, w3l, 2, enc_b3, Ff, 0, 512, 512, 0);
        ln_lrelu<<<gLN, blk, 0, stream>>>(dflag, Ff, E, enc_g3, enc_bt3);

        // 1x1 conv to z
        conv_mfma<1><<<dim3(32, 1, nb), blk, 0, stream>>>(
            dflag, E, 1024, 512, 1, 512, wmh, wml, 2, mlp_b, zbuf, 0, 64, 64, 0);

        // vector quantize -> D1 cols [0,64)
        vq_kernel<<<gT, blk, 0, stream>>>(dflag, zbuf, codebook, D1);

        // decoder (bf16 intermediates)
        conv_mfma<5><<<dim3(32, 8, nb), blk, 0, stream>>>(
            dflag, D1, 192, 0, 0, 192, wd1, nullptr, 0, dec_b1, Fh, 1, 1024, 1024, 0);
        ln_glu<<<gLN, blk, 0, stream>>>(dflag, Fh, D2, 640, dec_g1, dec_bt1);
        conv_mfma<5><<<dim3(32, 8, nb), blk, 0, stream>>>(
            dflag, D2, 640, 0, 0, 640, wd2, nullptr, 0, dec_b2, Fh, 1, 1024, 1024, 0);
        ln_glu<<<gLN, blk, 0, stream>>>(dflag, Fh, D3, 640, dec_g2, dec_bt2);
        conv_mfma<5><<<dim3(32, 1, nb), blk, 0, stream>>>(
            dflag, D3, 640, 0, 0, 640, wd3, nullptr, 0, dec_b3, d_out, 2, 80, 80, b0);
    }
}

// Round 6
// 4803.598 us; speedup vs baseline: 4.4673x; 1.0258x over previous
//
#include <hip/hip_runtime.h>
#include <hip/hip_bf16.h>
#include <cmath>

#define T_LEN 4096
#define BATCH 16
typedef __hip_bfloat16 bf16;
typedef unsigned short u16;
typedef float f32x4 __attribute__((ext_vector_type(4)));
typedef short s16x8 __attribute__((ext_vector_type(8)));
typedef unsigned short u16x8 __attribute__((ext_vector_type(8)));

__device__ __forceinline__ float ldx(const void* p, int dt, size_t i) {
    return dt ? __bfloat162float(((const bf16*)p)[i]) : ((const float*)p)[i];
}
__device__ __forceinline__ void stx(void* p, int dt, size_t i, float v) {
    if (dt) ((bf16*)p)[i] = __float2bfloat16(v);
    else ((float*)p)[i] = v;
}
__device__ __forceinline__ u16 f2b(float v) {
    bf16 h = __float2bfloat16(v);
    return *(u16*)&h;
}
__device__ __forceinline__ float b2f(u16 u) {
    return __bfloat162float(*(const bf16*)&u);
}

// ---------------------------------------------------------------- dtype probe
__global__ void detect_kernel(const float* __restrict__ x, int* __restrict__ flag) {
    __shared__ int s[256];
    int tid = threadIdx.x;
    int bad = 0;
    for (int i = tid; i < 2048; i += 256) {
        float v = x[i];
        if (!(fabsf(v) < 1e30f)) bad = 1;
    }
    s[tid] = bad;
    __syncthreads();
    for (int off = 128; off > 0; off >>= 1) {
        if (tid < off) s[tid] |= s[tid + off];
        __syncthreads();
    }
    if (tid == 0) *flag = s[0];
}

// ---------------------------------------------------------------- spk norm
__global__ void spk_norm_kernel(const int* __restrict__ dflag,
                                const void* __restrict__ spk,
                                float* __restrict__ out) {
    const int f = *dflag;
    int s = blockIdx.x, d = threadIdx.x;
    float v = ldx(spk, f, (size_t)s * 128 + d);
    __shared__ float red[128];
    red[d] = v * v;
    __syncthreads();
    for (int off = 64; off > 0; off >>= 1) {
        if (d < off) red[d] += red[d + off];
        __syncthreads();
    }
    float rs = rsqrtf(red[0]);
    out[s * 128 + d] = v * rs;
}

// ---------------------------------------------------------------- weight repack (coalesced, LDS transpose)
// dst: [K][ocp][Cinp] bf16, zero-padded. Max K = 5.
// wmode0: src [Cout][Cin][K]; tile 64 oc x 32 ic.
__global__ __launch_bounds__(256) void repack0_kernel(
    const int* __restrict__ dflag, const void* __restrict__ src,
    int Cout, int Cin, int K, int ocp, int Cinp,
    bf16* __restrict__ dsthi, bf16* __restrict__ dstlo) {
    const int F = *dflag;
    __shared__ u16 sh[64 * 32 * 5];
    __shared__ u16 sl[64 * 32 * 5];
    const int ic0 = blockIdx.x * 32;
    const int oc0 = blockIdx.y * 64;
    const int tid = threadIdx.x;
    const int N = 64 * 32 * K;
    for (int idx = tid; idx < N; idx += 256) {
        int ocl = idx / (32 * K);
        int r = idx % (32 * K);
        int icl = r / K, k = r % K;
        int oc = oc0 + ocl, ic = ic0 + icl;
        float v = 0.f;
        if (oc < Cout && ic < Cin)
            v = ldx(src, F, ((size_t)oc * Cin + ic) * K + k);
        u16 hb = f2b(v);
        sh[(ocl * 32 + icl) * K + k] = hb;
        sl[(ocl * 32 + icl) * K + k] = f2b(v - b2f(hb));
    }
    __syncthreads();
    const int M = K * 64 * 4;  // units of 8 ic
    for (int idx = tid; idx < M; idx += 256) {
        int k = idx / (64 * 4);
        int r = idx % (64 * 4);
        int ocl = r >> 2;
        int g8 = (r & 3) << 3;
        u16x8 h, l;
#pragma unroll
        for (int j = 0; j < 8; j++) {
            h[j] = sh[(ocl * 32 + g8 + j) * K + k];
            l[j] = sl[(ocl * 32 + g8 + j) * K + k];
        }
        size_t off = ((size_t)k * ocp + oc0 + ocl) * Cinp + ic0 + g8;
        *(u16x8*)&dsthi[off] = h;
        if (dstlo) *(u16x8*)&dstlo[off] = l;
    }
}

// wmode1 (convT): src [Cin][Cout][K]; W_eff[o][i][k]=src[i][o][K-1-k]; tile 64 ic x 32 oc.
__global__ __launch_bounds__(256) void repack1_kernel(
    const int* __restrict__ dflag, const void* __restrict__ src,
    int Cout, int Cin, int K, int ocp, int Cinp,
    bf16* __restrict__ dsthi) {
    const int F = *dflag;
    __shared__ u16 sh[64 * 32 * 5];
    const int ic0 = blockIdx.x * 64;
    const int oc0 = blockIdx.y * 32;
    const int tid = threadIdx.x;
    const int N = 64 * 32 * K;
    for (int idx = tid; idx < N; idx += 256) {
        int icl = idx / (32 * K);
        int r = idx % (32 * K);
        int ocl = r / K, k = r % K;
        int oc = oc0 + ocl, ic = ic0 + icl;
        float v = 0.f;
        if (oc < Cout && ic < Cin)
            v = ldx(src, F, ((size_t)ic * Cout + oc) * K + k);
        sh[(icl * 32 + ocl) * K + (K - 1 - k)] = f2b(v);
    }
    __syncthreads();
    const int M = K * 32 * 8;  // units of 8 ic
    for (int idx = tid; idx < M; idx += 256) {
        int k = idx / (32 * 8);
        int r = idx % (32 * 8);
        int ocl = r >> 3;
        int g8 = (r & 7) << 3;
        u16x8 h;
#pragma unroll
        for (int j = 0; j < 8; j++)
            h[j] = sh[((g8 + j) * 32 + ocl) * K + k];
        size_t off = ((size_t)k * ocp + oc0 + ocl) * Cinp + ic0 + g8;
        *(u16x8*)&dsthi[off] = h;
    }
}

// ---------------------------------------------------------------- x prep
// x external [b_abs][t][80] -> xp [b][t][192]: hi [0,96) (pad 0), lo [96,192)
__global__ void xprep_kernel(const int* __restrict__ dflag,
                             const void* __restrict__ x, int b0,
                             bf16* __restrict__ xp) {
    const int F = *dflag;
    int b = blockIdx.y;
    int t = blockIdx.x * 256 + threadIdx.x;
    size_t src = ((size_t)(b0 + b) * T_LEN + t) * 80;
    u16* row = (u16*)xp + ((size_t)b * T_LEN + t) * 192;
    for (int c4 = 0; c4 < 96; c4 += 4) {
        ushort4 h, l;
        u16* hp = (u16*)&h;
        u16* lp = (u16*)&l;
        for (int j = 0; j < 4; j++) {
            int c = c4 + j;
            float v = (c < 80) ? ldx(x, F, src + c) : 0.f;
            u16 hb = f2b(v);
            hp[j] = hb;
            lp[j] = f2b(v - b2f(hb));
        }
        *(ushort4*)&row[c4] = h;
        *(ushort4*)&row[96 + c4] = l;
    }
}

// ---------------------------------------------------------------- ye scatter
__global__ void ye_kernel(const int* __restrict__ y, int b0,
                          const float* __restrict__ spk_n,
                          bf16* __restrict__ D1, bf16* __restrict__ D2,
                          bf16* __restrict__ D3) {
    int b = blockIdx.y;
    int t = blockIdx.x * 256 + threadIdx.x;
    int idx = y[(size_t)(b0 + b) * T_LEN + t];
    const float* s = spk_n + (size_t)idx * 128;
    size_t r = (size_t)b * T_LEN + t;
    u16* p1 = (u16*)D1 + r * 192 + 64;
    u16* p2 = (u16*)D2 + r * 640 + 512;
    u16* p3 = (u16*)D3 + r * 640 + 512;
    for (int d4 = 0; d4 < 128; d4 += 4) {
        float4 v = *(const float4*)&s[d4];
        ushort4 h;
        h.x = f2b(v.x); h.y = f2b(v.y); h.z = f2b(v.z); h.w = f2b(v.w);
        *(ushort4*)&p1[d4] = h;
        *(ushort4*)&p2[d4] = h;
        *(ushort4*)&p3[d4] = h;
    }
}

// ---------------------------------------------------------------- MFMA conv
// Implicit GEMM: out[t][oc] = bias[oc] + sum_{ic,k} W[oc][ic][k] * A[t+k-PAD][ic]
// Block 128t x 128oc; 4 waves in 2x2; wave tile 64t x 64oc (4x4 16x16x32 frags).
// A (activations): staged in LDS (hi + optional lo). B (weights): read DIRECTLY
// from global per (tap,ni) fragment — lane-distinct 16B loads served by L1/L2;
// this keeps LDS at ~21 KB so occupancy is VGPR-bound (~4 blocks/CU).
// W: repacked [K][ocp][Cinp] bf16 (ocp = gridDim.y*128).
// aloMode: 0 never, 1 always, 2 iff flag==0. wloMode: 0 never, 2 iff flag==0.
template <int KK>
__global__ __launch_bounds__(256, 4) void conv_mfma(
    const int* __restrict__ dflag,
    const bf16* __restrict__ act, int RS, int loOff, int aloMode, int Cinp,
    const bf16* __restrict__ whi, const bf16* __restrict__ wlo, int wloMode,
    const void* __restrict__ bias,
    void* __restrict__ outp, int odt, int oRS, int ocMax, int boff) {
    constexpr int PAD = (KK - 1) / 2;
    constexpr int SROWS = 128 + KK - 1;
    const int F = *dflag;
    const bool useALo = (aloMode == 1) || (aloMode == 2 && F == 0);
    const bool useWLo = (wloMode == 2 && F == 0) && (wlo != nullptr);
    const int ocp = gridDim.y << 7;
    const int t0 = blockIdx.x * 128;
    const int oc0 = blockIdx.y * 128;
    const int b = blockIdx.z;
    const int tid = threadIdx.x;
    const int lane = tid & 63;
    const int wid = tid >> 6;
    const int widT = wid >> 1;       // 0..1 t half
    const int widN = wid & 1;        // 0..1 oc half
    const int l16 = lane & 15;
    const int quad = lane >> 4;
    const int q8 = quad * 8;

    __shared__ __align__(16) bf16 sA[2 * SROWS * 40];

    // per-lane weight base: row (oc0 + widN*64 + l16), k-offset q8
    const u16* wrow_hi = (const u16*)whi + (size_t)(oc0 + widN * 64 + l16) * Cinp + q8;
    const u16* wrow_lo = useWLo
        ? (const u16*)wlo + (size_t)(oc0 + widN * 64 + l16) * Cinp + q8 : nullptr;

    f32x4 acc[4][4];
#pragma unroll
    for (int i = 0; i < 4; i++)
#pragma unroll
        for (int j = 0; j < 4; j++) acc[i][j] = (f32x4){0.f, 0.f, 0.f, 0.f};

    const int nch = Cinp >> 5;
    for (int ch = 0; ch < nch; ch++) {
        const int ic0 = ch << 5;
        // ---- stage A tile (hi [+ lo]) rows t0-PAD..t0+127+PAD, 16B units
        for (int g = tid; g < SROWS * 4; g += 256) {
            int row = g >> 2, c8 = (g & 3) << 3;
            int t = t0 - PAD + row;
            u16x8 v = (u16x8){0, 0, 0, 0, 0, 0, 0, 0};
            u16x8 vl = (u16x8){0, 0, 0, 0, 0, 0, 0, 0};
            if (t >= 0 && t < T_LEN) {
                const u16* src = (const u16*)act + ((size_t)b * T_LEN + t) * RS + ic0 + c8;
                v = *(const u16x8*)src;
                if (useALo) vl = *(const u16x8*)(src + loOff);
            }
            *(u16x8*)&sA[row * 40 + c8] = v;
            if (useALo) *(u16x8*)&sA[(SROWS + row) * 40 + c8] = vl;
        }
        __syncthreads();

#pragma unroll
        for (int tap = 0; tap < KK; tap++) {
            // B fragments straight from global (L1/L2): 4 x 16B per lane
            s16x8 bfr[4];
#pragma unroll
            for (int ni = 0; ni < 4; ni++)
                bfr[ni] = *(const s16x8*)(wrow_hi +
                    ((size_t)tap * ocp + ni * 16) * Cinp + ic0);
#pragma unroll
            for (int mi = 0; mi < 4; mi++) {
                int row = widT * 64 + mi * 16 + l16 + tap;
                s16x8 a = *(const s16x8*)&sA[row * 40 + q8];
#pragma unroll
                for (int ni = 0; ni < 4; ni++)
                    acc[mi][ni] = __builtin_amdgcn_mfma_f32_16x16x32_bf16(
                        a, bfr[ni], acc[mi][ni], 0, 0, 0);
                if (useALo) {
                    s16x8 al = *(const s16x8*)&sA[(SROWS + row) * 40 + q8];
#pragma unroll
                    for (int ni = 0; ni < 4; ni++)
                        acc[mi][ni] = __builtin_amdgcn_mfma_f32_16x16x32_bf16(
                            al, bfr[ni], acc[mi][ni], 0, 0, 0);
                }
            }
        }
        if (useWLo) {
#pragma unroll
            for (int tap = 0; tap < KK; tap++) {
                s16x8 bfr[4];
#pragma unroll
                for (int ni = 0; ni < 4; ni++)
                    bfr[ni] = *(const s16x8*)(wrow_lo +
                        ((size_t)tap * ocp + ni * 16) * Cinp + ic0);
#pragma unroll
                for (int mi = 0; mi < 4; mi++) {
                    int row = widT * 64 + mi * 16 + l16 + tap;
                    s16x8 a = *(const s16x8*)&sA[row * 40 + q8];
#pragma unroll
                    for (int ni = 0; ni < 4; ni++)
                        acc[mi][ni] = __builtin_amdgcn_mfma_f32_16x16x32_bf16(
                            a, bfr[ni], acc[mi][ni], 0, 0, 0);
                }
            }
        }
        __syncthreads();
    }

    // ---- epilogue: D row = quad*4+r (t), col = l16 (oc)
#pragma unroll
    for (int ni = 0; ni < 4; ni++) {
        int oc = oc0 + widN * 64 + ni * 16 + l16;
        if (oc >= ocMax) continue;
        float bv = ldx(bias, F, oc);
#pragma unroll
        for (int mi = 0; mi < 4; mi++) {
#pragma unroll
            for (int r = 0; r < 4; r++) {
                int t = t0 + widT * 64 + mi * 16 + quad * 4 + r;
                float v = acc[mi][ni][r] + bv;
                size_t off = ((size_t)(b + boff) * T_LEN + t) * (size_t)oRS + oc;
                if (odt == 0) ((float*)outp)[off] = v;
                else if (odt == 1) ((bf16*)outp)[off] = __float2bfloat16(v);
                else stx(outp, F, off, v);
            }
        }
    }
}

// ---------------------------------------------------------------- LN + LeakyReLU
// in: f32 [b][t][512]; out: bf16 pair [b][t][1024] (hi 0..512, lo 512..1024)
__global__ __launch_bounds__(256) void ln_lrelu(
    const int* __restrict__ dflag, const float* __restrict__ Fin,
    bf16* __restrict__ E, const void* __restrict__ g, const void* __restrict__ bt) {
    const int Fl = *dflag;
    int b = blockIdx.y;
    int t = blockIdx.x * 4 + (threadIdx.x >> 6);
    int lane = threadIdx.x & 63;
    const float* row = Fin + ((size_t)b * T_LEN + t) * 512 + lane * 8;
    float vv[8];
    *(float4*)&vv[0] = *(const float4*)row;
    *(float4*)&vv[4] = *(const float4*)(row + 4);
    float s = 0.f, s2 = 0.f;
#pragma unroll
    for (int j = 0; j < 8; j++) { s += vv[j]; s2 += vv[j] * vv[j]; }
    for (int m = 32; m; m >>= 1) {
        s += __shfl_xor(s, m);
        s2 += __shfl_xor(s2, m);
    }
    float mean = s / 512.f;
    float var = s2 / 512.f - mean * mean;
    float rstd = rsqrtf(var + 1e-5f);
    u16* eo = (u16*)E + ((size_t)b * T_LEN + t) * 1024 + lane * 8;
    ushort4 h[2], l[2];
#pragma unroll
    for (int j = 0; j < 8; j++) {
        int c = lane * 8 + j;
        float v = (vv[j] - mean) * rstd * ldx(g, Fl, c) + ldx(bt, Fl, c);
        v = v >= 0.f ? v : 0.2f * v;
        u16 hb = f2b(v);
        ((u16*)h)[j] = hb;
        ((u16*)l)[j] = f2b(v - b2f(hb));
    }
    *(ushort4*)&eo[0] = h[0];
    *(ushort4*)&eo[4] = h[1];
    *(ushort4*)&eo[512] = l[0];
    *(ushort4*)&eo[516] = l[1];
}

// ---------------------------------------------------------------- LN + GLU
__global__ __launch_bounds__(256) void ln_glu(
    const int* __restrict__ dflag, const bf16* __restrict__ Fin,
    bf16* __restrict__ D, int oRS, const void* __restrict__ g,
    const void* __restrict__ bt) {
    const int Fl = *dflag;
    int b = blockIdx.y;
    int t = blockIdx.x * 4 + (threadIdx.x >> 6);
    int lane = threadIdx.x & 63;
    const u16* row = (const u16*)Fin + ((size_t)b * T_LEN + t) * 1024;
    ushort4 ua[2], ug[2];
    ua[0] = *(const ushort4*)&row[lane * 8];
    ua[1] = *(const ushort4*)&row[lane * 8 + 4];
    ug[0] = *(const ushort4*)&row[512 + lane * 8];
    ug[1] = *(const ushort4*)&row[512 + lane * 8 + 4];
    float av[8], gv[8];
#pragma unroll
    for (int j = 0; j < 8; j++) {
        av[j] = b2f(((u16*)ua)[j]);
        gv[j] = b2f(((u16*)ug)[j]);
    }
    float s = 0.f, s2 = 0.f;
#pragma unroll
    for (int j = 0; j < 8; j++) {
        s += av[j] + gv[j];
        s2 += av[j] * av[j] + gv[j] * gv[j];
    }
    for (int m = 32; m; m >>= 1) {
        s += __shfl_xor(s, m);
        s2 += __shfl_xor(s2, m);
    }
    float mean = s / 1024.f;
    float var = s2 / 1024.f - mean * mean;
    float rstd = rsqrtf(var + 1e-5f);
    ushort4 o[2];
#pragma unroll
    for (int j = 0; j < 8; j++) {
        int c = lane * 8 + j;
        float a = (av[j] - mean) * rstd * ldx(g, Fl, c) + ldx(bt, Fl, c);
        float gg = (gv[j] - mean) * rstd * ldx(g, Fl, 512 + c) + ldx(bt, Fl, 512 + c);
        ((u16*)o)[j] = f2b(a / (1.f + expf(-gg)));
    }
    u16* op = (u16*)D + ((size_t)b * T_LEN + t) * oRS + lane * 8;
    *(ushort4*)&op[0] = o[0];
    *(ushort4*)&op[4] = o[1];
}

// ---------------------------------------------------------------- VQ
__global__ __launch_bounds__(256) void vq_kernel(
    const int* __restrict__ dflag, const float* __restrict__ z,
    const void* __restrict__ cb, bf16* __restrict__ D1) {
    const int F = *dflag;
    int b = blockIdx.y;
    int t = blockIdx.x * 256 + threadIdx.x;
    int tid = threadIdx.x;

    __shared__ float sCB[128 * 64];
    __shared__ float sCC[128];

    float zr[64];
    const float* zp = z + ((size_t)b * T_LEN + t) * 64;
#pragma unroll
    for (int d4 = 0; d4 < 64; d4 += 4) *(float4*)&zr[d4] = *(const float4*)&zp[d4];
    float zz = 0.f;
#pragma unroll
    for (int d = 0; d < 64; d++) zz += zr[d] * zr[d];

    float best = 3.4e38f;
    int bidx = 0;
    for (int chunk = 0; chunk < 4; chunk++) {
        __syncthreads();
        for (int i = tid; i < 8192; i += 256)
            sCB[i] = ldx(cb, F, (size_t)chunk * 8192 + i);
        __syncthreads();
        if (tid < 128) {
            float cc = 0.f;
#pragma unroll 8
            for (int d = 0; d < 64; d++) {
                float cv = sCB[tid * 64 + d];
                cc += cv * cv;
            }
            sCC[tid] = cc;
        }
        __syncthreads();
        for (int c = 0; c < 128; c++) {
            const float* cp = &sCB[c * 64];
            float dot = 0.f;
#pragma unroll
            for (int d = 0; d < 64; d++) dot += zr[d] * cp[d];
            float dist = zz + sCC[c] - 2.f * dot;
            if (dist < best) { best = dist; bidx = chunk * 128 + c; }
        }
    }
    u16* out = (u16*)D1 + ((size_t)b * T_LEN + t) * 192;
    for (int d4 = 0; d4 < 64; d4 += 4) {
        ushort4 h;
        h.x = f2b(ldx(cb, F, (size_t)bidx * 64 + d4));
        h.y = f2b(ldx(cb, F, (size_t)bidx * 64 + d4 + 1));
        h.z = f2b(ldx(cb, F, (size_t)bidx * 64 + d4 + 2));
        h.w = f2b(ldx(cb, F, (size_t)bidx * 64 + d4 + 3));
        *(ushort4*)&out[d4] = h;
    }
}

// ---------------------------------------------------------------- launch
extern "C" void kernel_launch(void* const* d_in, const int* in_sizes, int n_in,
                              void* d_out, int out_size, void* d_ws,
                              size_t ws_size, hipStream_t stream) {
    const void* x = d_in[0];
    const int* y = (const int*)d_in[1];
    const void* enc_w1 = d_in[2];  const void* enc_b1 = d_in[3];
    const void* enc_g1 = d_in[4];  const void* enc_bt1 = d_in[5];
    const void* enc_w2 = d_in[6];  const void* enc_b2 = d_in[7];
    const void* enc_g2 = d_in[8];  const void* enc_bt2 = d_in[9];
    const void* enc_w3 = d_in[10]; const void* enc_b3 = d_in[11];
    const void* enc_g3 = d_in[12]; const void* enc_bt3 = d_in[13];
    const void* mlp_w = d_in[14];  const void* mlp_b = d_in[15];
    const void* codebook = d_in[16];
    const void* spk_emb = d_in[17];
    const void* dec_w1 = d_in[18]; const void* dec_b1 = d_in[19];
    const void* dec_g1 = d_in[20]; const void* dec_bt1 = d_in[21];
    const void* dec_w2 = d_in[22]; const void* dec_b2 = d_in[23];
    const void* dec_g2 = d_in[24]; const void* dec_bt2 = d_in[25];
    const void* dec_w3 = d_in[26]; const void* dec_b3 = d_in[27];

    // repacked weight sizes (elements)
    const size_t SW1 = (size_t)5 * 512 * 96;
    const size_t SW2 = (size_t)5 * 512 * 512;
    const size_t SW3 = SW2;
    const size_t SWM = (size_t)128 * 512;
    const size_t SD1 = (size_t)5 * 1024 * 192;
    const size_t SD2 = (size_t)5 * 1024 * 640;
    const size_t SD3 = (size_t)5 * 128 * 640;
    const size_t HI_TOT = SW1 + SW2 + SW3 + SWM + SD1 + SD2 + SD3;
    const size_t LO_TOT = SW1 + SW2 + SW3 + SWM;

    const size_t PB = (size_t)T_LEN * (192 * 2 + 1024 * 2 + 2048 + 64 * 4 + 640 * 2 + 640 * 2);
    const size_t FIXED = 256 + 65536 + (HI_TOT + LO_TOT) * 2;

    int nb = BATCH;
    while (nb > 1 && FIXED + (size_t)nb * PB > ws_size) nb >>= 1;

    char* p = (char*)d_ws;
    int* dflag = (int*)p;        p += 256;
    float* spk_n = (float*)p;    p += 65536;
    bf16* w1h = (bf16*)p;        p += SW1 * 2;
    bf16* w2h = (bf16*)p;        p += SW2 * 2;
    bf16* w3h = (bf16*)p;        p += SW3 * 2;
    bf16* wmh = (bf16*)p;        p += SWM * 2;
    bf16* wd1 = (bf16*)p;        p += SD1 * 2;
    bf16* wd2 = (bf16*)p;        p += SD2 * 2;
    bf16* wd3 = (bf16*)p;        p += SD3 * 2;
    bf16* w1l = (bf16*)p;        p += SW1 * 2;
    bf16* w2l = (bf16*)p;        p += SW2 * 2;
    bf16* w3l = (bf16*)p;        p += SW3 * 2;
    bf16* wml = (bf16*)p;        p += SWM * 2;
    bf16* xp = (bf16*)p;         p += (size_t)nb * T_LEN * 192 * 2;  // aliases D1
    bf16* E = (bf16*)p;          p += (size_t)nb * T_LEN * 1024 * 2;
    char* Fb = p;                p += (size_t)nb * T_LEN * 2048;     // f32x512 / bf16x1024
    float* zbuf = (float*)p;     p += (size_t)nb * T_LEN * 64 * 4;
    bf16* D2 = (bf16*)p;         p += (size_t)nb * T_LEN * 640 * 2;
    bf16* D3 = (bf16*)p;
    bf16* D1 = xp;
    float* Ff = (float*)Fb;
    bf16* Fh = (bf16*)Fb;

    dim3 blk(256);

    detect_kernel<<<1, 256, 0, stream>>>((const float*)x, dflag);
    spk_norm_kernel<<<128, 128, 0, stream>>>(dflag, spk_emb, spk_n);

    // repack weights (coalesced tiles)
    repack0_kernel<<<dim3(3, 8), blk, 0, stream>>>(dflag, enc_w1, 512, 80, 5, 512, 96, w1h, w1l);
    repack0_kernel<<<dim3(16, 8), blk, 0, stream>>>(dflag, enc_w2, 512, 512, 5, 512, 512, w2h, w2l);
    repack0_kernel<<<dim3(16, 8), blk, 0, stream>>>(dflag, enc_w3, 512, 512, 5, 512, 512, w3h, w3l);
    repack0_kernel<<<dim3(16, 2), blk, 0, stream>>>(dflag, mlp_w, 64, 512, 1, 128, 512, wmh, wml);
    repack1_kernel<<<dim3(3, 32), blk, 0, stream>>>(dflag, dec_w1, 1024, 192, 5, 1024, 192, wd1);
    repack1_kernel<<<dim3(10, 32), blk, 0, stream>>>(dflag, dec_w2, 1024, 640, 5, 1024, 640, wd2);
    repack1_kernel<<<dim3(10, 4), blk, 0, stream>>>(dflag, dec_w3, 80, 640, 5, 128, 640, wd3);

    for (int b0 = 0; b0 < BATCH; b0 += nb) {
        dim3 gT(T_LEN / 256, nb);
        dim3 gLN(T_LEN / 4, nb);

        xprep_kernel<<<gT, blk, 0, stream>>>(dflag, x, b0, xp);

        // encoder (f32-pair intermediates)
        conv_mfma<5><<<dim3(32, 4, nb), blk, 0, stream>>>(
            dflag, xp, 192, 96, 2, 96, w1h, w1l, 2, enc_b1, Ff, 0, 512, 512, 0);
        // ye written after enc1 consumed xp (D1 aliases xp)
        ye_kernel<<<gT, blk, 0, stream>>>(y, b0, spk_n, D1, D2, D3);
        ln_lrelu<<<gLN, blk, 0, stream>>>(dflag, Ff, E, enc_g1, enc_bt1);
        conv_mfma<5><<<dim3(32, 4, nb), blk, 0, stream>>>(
            dflag, E, 1024, 512, 1, 512, w2h, w2l, 2, enc_b2, Ff, 0, 512, 512, 0);
        ln_lrelu<<<gLN, blk, 0, stream>>>(dflag, Ff, E, enc_g2, enc_bt2);
        conv_mfma<5><<<dim3(32, 4, nb), blk, 0, stream>>>(
            dflag, E, 1024, 512, 1, 512, w3h, w3l, 2, enc_b3, Ff, 0, 512, 512, 0);
        ln_lrelu<<<gLN, blk, 0, stream>>>(dflag, Ff, E, enc_g3, enc_bt3);

        // 1x1 conv to z
        conv_mfma<1><<<dim3(32, 1, nb), blk, 0, stream>>>(
            dflag, E, 1024, 512, 1, 512, wmh, wml, 2, mlp_b, zbuf, 0, 64, 64, 0);

        // vector quantize -> D1 cols [0,64)
        vq_kernel<<<gT, blk, 0, stream>>>(dflag, zbuf, codebook, D1);

        // decoder (bf16 intermediates)
        conv_mfma<5><<<dim3(32, 8, nb), blk, 0, stream>>>(
            dflag, D1, 192, 0, 0, 192, wd1, nullptr, 0, dec_b1, Fh, 1, 1024, 1024, 0);
        ln_glu<<<gLN, blk, 0, stream>>>(dflag, Fh, D2, 640, dec_g1, dec_bt1);
        conv_mfma<5><<<dim3(32, 8, nb), blk, 0, stream>>>(
            dflag, D2, 640, 0, 0, 640, wd2, nullptr, 0, dec_b2, Fh, 1, 1024, 1024, 0);
        ln_glu<<<gLN, blk, 0, stream>>>(dflag, Fh, D3, 640, dec_g2, dec_bt2);
        conv_mfma<5><<<dim3(32, 1, nb), blk, 0, stream>>>(
            dflag, D3, 640, 0, 0, 640, wd3, nullptr, 0, dec_b3, d_out, 2, 80, 80, b0);
    }
}